// Round 6
// baseline (436.817 us; speedup 1.0000x reference)
//
#include <hip/hip_runtime.h>
#include <hip/hip_bf16.h>
#include <math.h>

typedef unsigned short u16;
typedef unsigned int u32;
typedef u16 u16x8 __attribute__((ext_vector_type(8)));
typedef __bf16 bf16x8 __attribute__((ext_vector_type(8)));
typedef float f32x4 __attribute__((ext_vector_type(4)));

#define MODE_GELU 1
#define MODE_RESF32 2
#define MODE_QKV 3

template <typename T, typename F>
__device__ __forceinline__ T bitcast(F f) { return __builtin_bit_cast(T, f); }

__device__ __forceinline__ u16 f2bf(float f) {
    unsigned int u = __float_as_uint(f);
    u = (u + 0x7fffu + ((u >> 16) & 1u)) >> 16;
    return (u16)u;
}

// pack two floats into (lo | hi<<16) bf16 pair — pure C, no inline asm
__device__ __forceinline__ u32 packbf(float lo, float hi) {
    return (u32)f2bf(lo) | ((u32)f2bf(hi) << 16);
}

__device__ __forceinline__ void gl_lds16(const u16* g, u16* l) {
    __builtin_amdgcn_global_load_lds(
        (const __attribute__((address_space(1))) unsigned int*)(const void*)g,
        (__attribute__((address_space(3))) unsigned int*)(void*)l,
        16, 0, 0);
}

// ---------------------------------------------------------------------------
// prep: all 6 weight transposes (W[K][N] -> WT[N][K] bf16) + bias concat,
// one kernel. tiles: wq 576 | wk 576 | wv 576 | wo 576 | w1 2304 | w2 2304.
// ---------------------------------------------------------------------------
__global__ __launch_bounds__(256) void prep_kernel(
    const float* __restrict__ wq, const float* __restrict__ wk,
    const float* __restrict__ wv, const float* __restrict__ wo,
    const float* __restrict__ w1, const float* __restrict__ w2,
    const float* __restrict__ bq, const float* __restrict__ bk,
    const float* __restrict__ bv,
    u16* __restrict__ wqkvT, u16* __restrict__ woT,
    u16* __restrict__ w1T, u16* __restrict__ w2T, float* __restrict__ bqkv)
{
    const int blk = blockIdx.x;
    if (blk >= 6912) {  // bias concat
        const int t = (blk - 6912) * 256 + threadIdx.x;
        if (t < 2304)
            bqkv[t] = t < 768 ? bq[t] : (t < 1536 ? bk[t - 768] : bv[t - 1536]);
        return;
    }
    const float* W; u16* WT; int Krows, Ncols, lt;
    if (blk < 576)       { W = wq; WT = wqkvT;                       Krows = 768;  Ncols = 768;  lt = blk; }
    else if (blk < 1152) { W = wk; WT = wqkvT + (size_t)768 * 768;   Krows = 768;  Ncols = 768;  lt = blk - 576; }
    else if (blk < 1728) { W = wv; WT = wqkvT + (size_t)1536 * 768;  Krows = 768;  Ncols = 768;  lt = blk - 1152; }
    else if (blk < 2304) { W = wo; WT = woT;                         Krows = 768;  Ncols = 768;  lt = blk - 1728; }
    else if (blk < 4608) { W = w1; WT = w1T;                         Krows = 768;  Ncols = 3072; lt = blk - 2304; }
    else                 { W = w2; WT = w2T;                         Krows = 3072; Ncols = 768;  lt = blk - 4608; }
    const int ktiles = Krows >> 5;
    const int k0 = (lt % ktiles) * 32, n0 = (lt / ktiles) * 32;

    __shared__ float tile[32][33];
    const int tx = threadIdx.x & 31, ty = threadIdx.x >> 5;
#pragma unroll
    for (int j = 0; j < 32; j += 8)
        tile[ty + j][tx] = W[(size_t)(k0 + ty + j) * Ncols + n0 + tx];
    __syncthreads();
#pragma unroll
    for (int j = 0; j < 32; j += 8)
        WT[(size_t)(n0 + ty + j) * Krows + k0 + tx] = f2bf(tile[tx][ty + j]);
}

// ---------------------------------------------------------------------------
// LayerNorm (ddof=1, divide by std+eps, scalar gamma/beta), fp32 -> bf16
// ---------------------------------------------------------------------------
__global__ __launch_bounds__(256) void ln_kernel(
    const float* __restrict__ X, u16* __restrict__ Y,
    const float* __restrict__ gp, const float* __restrict__ bp)
{
    __shared__ float sbuf[8];
    const int row = blockIdx.x, t = threadIdx.x;
    const float* xr = X + (size_t)row * 768;
    float v0 = xr[t], v1 = xr[t + 256], v2 = xr[t + 512];
    float s = v0 + v1 + v2;
    float q = v0 * v0 + v1 * v1 + v2 * v2;
#pragma unroll
    for (int m = 1; m < 64; m <<= 1) {
        s += __shfl_xor(s, m, 64);
        q += __shfl_xor(q, m, 64);
    }
    const int wave = t >> 6, lane = t & 63;
    if (lane == 0) { sbuf[wave] = s; sbuf[4 + wave] = q; }
    __syncthreads();
    s = sbuf[0] + sbuf[1] + sbuf[2] + sbuf[3];
    q = sbuf[4] + sbuf[5] + sbuf[6] + sbuf[7];
    const float mean = s * (1.0f / 768.0f);
    float ssd = q - 768.0f * mean * mean;
    ssd = fmaxf(ssd, 0.0f);
    const float stdv = sqrtf(ssd * (1.0f / 767.0f));
    const float scale = gp[0] / (stdv + 1e-5f);
    const float beta = bp[0];
    u16* yr = Y + (size_t)row * 768;
    yr[t]       = f2bf((v0 - mean) * scale + beta);
    yr[t + 256] = f2bf((v1 - mean) * scale + beta);
    yr[t + 512] = f2bf((v2 - mean) * scale + beta);
}

// ---------------------------------------------------------------------------
// GEMM (m97 structure): C[M][N] = A @ BT^T + bias, global_load_lds staging.
// 128x128 tile, BK=64, 256 thr = 4 waves (2x2), linear LDS.
// MODE_QKV: N=2304; Q/K written normal; V written transposed per-head via
// LDS-staged tile transpose (coalesced V^T stores).
// ---------------------------------------------------------------------------
template <int MODE>
__global__ __launch_bounds__(256) void gemm_kernel(
    const u16* __restrict__ A, const u16* __restrict__ BT,
    const float* __restrict__ bias, const float* __restrict__ res,
    void* __restrict__ out0, void* __restrict__ out1, void* __restrict__ out2,
    int M, int N, int K)
{
    __shared__ u16 sh[2 * 128 * 64];          // As | Bs; reused for V-transpose
    u16* Asb = sh;
    u16* Bsb = sh + 8192;
    const int t = threadIdx.x;
    const int lane = t & 63, wave = t >> 6;
    const int wr = wave >> 1, wc = wave & 1;
    const int g = lane >> 4, c = lane & 15;
    const int bm = blockIdx.x, bn = blockIdx.y;

    const int srow = wave * 32 + (lane >> 3);
    const int scol = (lane & 7) * 8;
    const u16* Ag = A + (size_t)(bm * 128 + srow) * K + scol;
    const u16* Bg = BT + (size_t)(bn * 128 + srow) * K + scol;
    u16* AsW = Asb + wave * 2048;
    u16* BsW = Bsb + wave * 2048;

    f32x4 acc[4][4] = {};

    for (int k0 = 0; k0 < K; k0 += 64) {
        __syncthreads();
#pragma unroll
        for (int it = 0; it < 4; it++) {
            gl_lds16(Ag + (size_t)(it * 8) * K + k0, AsW + it * 512);
            gl_lds16(Bg + (size_t)(it * 8) * K + k0, BsW + it * 512);
        }
        __syncthreads();
#pragma unroll
        for (int kk = 0; kk < 2; kk++) {
            bf16x8 af[4], bfr[4];
#pragma unroll
            for (int m = 0; m < 4; m++)
                af[m] = *(const bf16x8*)&Asb[(wr * 64 + m * 16 + c) * 64 + kk * 32 + g * 8];
#pragma unroll
            for (int n = 0; n < 4; n++)
                bfr[n] = *(const bf16x8*)&Bsb[(wc * 64 + n * 16 + c) * 64 + kk * 32 + g * 8];
#pragma unroll
            for (int m = 0; m < 4; m++)
#pragma unroll
                for (int n = 0; n < 4; n++)
                    acc[m][n] = __builtin_amdgcn_mfma_f32_16x16x32_bf16(
                        af[m], bfr[n], acc[m][n], 0, 0, 0);
        }
    }

    if constexpr (MODE == MODE_QKV) {
        if (bn >= 12) {
            // ---- V section: LDS tile transpose, coalesced V^T stores ----
            __syncthreads();
#pragma unroll
            for (int m = 0; m < 4; m++) {
#pragma unroll
                for (int n = 0; n < 4; n++) {
                    const int colL = wc * 64 + n * 16 + c;
                    const int rowLb = wr * 64 + m * 16 + 4 * g;
                    const float bv = bias[bn * 128 + colL];
                    const u32 x0 = packbf(acc[m][n][0] + bv, acc[m][n][1] + bv);
                    const u32 x1 = packbf(acc[m][n][2] + bv, acc[m][n][3] + bv);
                    const int elem = colL * 128 + (rowLb ^ ((colL & 15) << 3));
                    ((u32*)sh)[elem >> 1] = x0;
                    ((u32*)sh)[(elem >> 1) + 1] = x1;
                }
            }
            __syncthreads();
            const int bn_off = bn - 12;
            const int bb = bm >> 3, kvb = (bm & 7) * 128;
            const int j8 = (t & 7) * 8;
#pragma unroll
            for (int it = 0; it < 4; it++) {
                const int colL2 = it * 32 + (t >> 3);
                const int gcol = bn_off * 128 + colL2;
                const int hh = gcol >> 6, d = gcol & 63;
                const size_t obase = ((size_t)(bb * 12 + hh) << 16) + ((size_t)d << 10) + kvb;
                const int X = (colL2 & 15) << 3;
#pragma unroll
                for (int half = 0; half < 2; half++) {
                    const int rowL2 = half * 64 + j8;
                    const int elem = colL2 * 128 + (rowL2 ^ X);
                    *(u16x8*)((u16*)out2 + obase + rowL2) = *(const u16x8*)&sh[elem];
                }
            }
            return;
        }
    }

#pragma unroll
    for (int m = 0; m < 4; m++) {
        const int row = bm * 128 + wr * 64 + m * 16 + 4 * g;
#pragma unroll
        for (int n = 0; n < 4; n++) {
            const int col = bn * 128 + wc * 64 + n * 16 + c;
            const float bv = bias[col];
#pragma unroll
            for (int i = 0; i < 4; i++) {
                float v = acc[m][n][i] + bv;
                if constexpr (MODE == MODE_GELU) {
                    v = 0.5f * v * (1.0f + erff(v * 0.70710678118654752f));
                    ((u16*)out0)[(size_t)(row + i) * N + col] = f2bf(v);
                } else if constexpr (MODE == MODE_RESF32) {
                    const size_t idx = (size_t)(row + i) * N + col;
                    ((float*)out0)[idx] = v + res[idx];
                } else {  // MODE_QKV, bn < 12: Q or K, normal layout
                    const int sect = (col >= 768) ? 1 : 0;
                    const int colm = col - sect * 768;
                    u16* dst = sect ? (u16*)out1 : (u16*)out0;
                    dst[(size_t)(row + i) * 768 + colm] = f2bf(v);
                }
            }
        }
    }
}

// ---------------------------------------------------------------------------
// Flash attention, swapped QK^T + in-register softmax, ZERO LDS.
// grid 1536 linear; XCD-aware: head = (l&7)*12 + (l>>3)/16 so each head's
// 16 q-blocks share one XCD L2 (K+V head = 256 KB, L2-resident).
// 256 thr = 4 waves x 16 q-rows, KV tile 64. V^T read direct from global.
// Defer-max online softmax (THR=8 in exp2 units).
// ---------------------------------------------------------------------------
__global__ __launch_bounds__(256) void attn_kernel(
    const u16* __restrict__ Q, const u16* __restrict__ Kg,
    const u16* __restrict__ Vt_g, u16* __restrict__ O)
{
    const int t = threadIdx.x, lane = t & 63, wave = t >> 6;
    const int g = lane >> 4, c = lane & 15;
    const int l = blockIdx.x;
    const int pos = l >> 3;
    const int bh = (l & 7) * 12 + (pos >> 4);
    const int qt = pos & 15;
    const int b = bh / 12, h = bh % 12;
    const size_t rowb = (size_t)b * 1024;
    const int q0 = qt * 64 + wave * 16;

    // Q fragment scaled by 0.125*log2(e) (scores land in exp2 units)
    bf16x8 qf[2];
    {
        const u16* qp = Q + (rowb + q0 + c) * 768 + h * 64 + g * 8;
        u16x8 r0 = *(const u16x8*)qp;
        u16x8 r1 = *(const u16x8*)(qp + 32);
        bf16x8 q0v, q1v;
#pragma unroll
        for (int j = 0; j < 8; j++) {
            q0v[j] = (__bf16)(__uint_as_float(((u32)r0[j]) << 16) * 0.18033688011112042f);
            q1v[j] = (__bf16)(__uint_as_float(((u32)r1[j]) << 16) * 0.18033688011112042f);
        }
        qf[0] = q0v;
        qf[1] = q1v;
    }

    // K rows permuted: frag row c of mfma n -> kv = (n>>1)*32+(c>>2)*8+(n&1)*4+(c&3)
    const u16* kbase = Kg + rowb * 768 + h * 64 + g * 8;
    int kro[4];
#pragma unroll
    for (int n = 0; n < 4; n++)
        kro[n] = ((n >> 1) * 32 + ((c >> 2) * 8) + ((n & 1) * 4) + (c & 3)) * 768;

    // V^T B-fragment base: lane (g,c) reads V^T[d=n*16+c][kv0+kk*32+g*8..]
    const u16* vbase = Vt_g + (size_t)bh * 65536 + (size_t)c * 1024 + g * 8;

    float m_run = -1e30f, l_run = 0.f;
    f32x4 o_acc[4] = {};

    bf16x8 kf[8], kn[8];
#pragma unroll
    for (int n = 0; n < 4; n++) {
        kf[2 * n]     = *(const bf16x8*)(kbase + kro[n]);
        kf[2 * n + 1] = *(const bf16x8*)(kbase + kro[n] + 32);
    }

    const int srcb = (lane & 48) | ((lane >> 2) & 12);   // = 20*g

    for (int kvt = 0; kvt < 16; ++kvt) {
        const int kv0 = kvt * 64;

        // S^T[kv][q=c] in exp2 units
        f32x4 s[4] = {};
#pragma unroll
        for (int n = 0; n < 4; n++) {
            s[n] = __builtin_amdgcn_mfma_f32_16x16x32_bf16(kf[2 * n],     qf[0], s[n], 0, 0, 0);
            s[n] = __builtin_amdgcn_mfma_f32_16x16x32_bf16(kf[2 * n + 1], qf[1], s[n], 0, 0, 0);
        }

        // V fragments for this tile (global, L2-resident; arrive under softmax)
        bf16x8 vf[8];
#pragma unroll
        for (int n = 0; n < 4; n++) {
            vf[2 * n]     = *(const bf16x8*)(vbase + n * 16384 + kv0);
            vf[2 * n + 1] = *(const bf16x8*)(vbase + n * 16384 + kv0 + 32);
        }
        // prefetch next K tile
        if (kvt < 15) {
            const u16* kpn = kbase + (size_t)(kvt + 1) * 64 * 768;
#pragma unroll
            for (int n = 0; n < 4; n++) {
                kn[2 * n]     = *(const bf16x8*)(kpn + kro[n]);
                kn[2 * n + 1] = *(const bf16x8*)(kpn + kro[n] + 32);
            }
        }

        // tree max (v_max3-friendly)
        float m0 = fmaxf(fmaxf(s[0][0], s[0][1]), fmaxf(s[0][2], s[0][3]));
        float m1 = fmaxf(fmaxf(s[1][0], s[1][1]), fmaxf(s[1][2], s[1][3]));
        float m2 = fmaxf(fmaxf(s[2][0], s[2][1]), fmaxf(s[2][2], s[2][3]));
        float m3 = fmaxf(fmaxf(s[3][0], s[3][1]), fmaxf(s[3][2], s[3][3]));
        float mx = fmaxf(fmaxf(m0, m1), fmaxf(m2, m3));
        mx = fmaxf(mx, __shfl_xor(mx, 16, 64));
        mx = fmaxf(mx, __shfl_xor(mx, 32, 64));

        // defer-max: only rescale when the running max grew by > 8 (2^8 bound)
        if (!__all(mx <= m_run + 8.0f)) {
            const float mnew = fmaxf(m_run, mx);
            const float resc = exp2f(m_run - mnew);
            m_run = mnew;
            l_run *= resc;
            f32x4 rq;
#pragma unroll
            for (int i = 0; i < 4; i++) rq[i] = __shfl(resc, srcb + i, 64);
#pragma unroll
            for (int n = 0; n < 4; n++) o_acc[n] *= rq;
        }

        float r0 = 0.f, r1 = 0.f, r2 = 0.f, r3 = 0.f;
#pragma unroll
        for (int i = 0; i < 4; i++) {
            s[0][i] = exp2f(s[0][i] - m_run); r0 += s[0][i];
            s[1][i] = exp2f(s[1][i] - m_run); r1 += s[1][i];
            s[2][i] = exp2f(s[2][i] - m_run); r2 += s[2][i];
            s[3][i] = exp2f(s[3][i] - m_run); r3 += s[3][i];
        }
        float rs = (r0 + r1) + (r2 + r3);
        rs += __shfl_xor(rs, 16, 64);
        rs += __shfl_xor(rs, 32, 64);
        l_run += rs;

        // pack P into PV A-fragments (lane-local by construction)
        bf16x8 pa0, pa1;
#pragma unroll
        for (int i = 0; i < 4; i++) {
            pa0[i]     = (__bf16)s[0][i];
            pa0[4 + i] = (__bf16)s[1][i];
            pa1[i]     = (__bf16)s[2][i];
            pa1[4 + i] = (__bf16)s[3][i];
        }

        // PV
#pragma unroll
        for (int n = 0; n < 4; n++) {
            o_acc[n] = __builtin_amdgcn_mfma_f32_16x16x32_bf16(pa0, vf[2 * n],     o_acc[n], 0, 0, 0);
            o_acc[n] = __builtin_amdgcn_mfma_f32_16x16x32_bf16(pa1, vf[2 * n + 1], o_acc[n], 0, 0, 0);
        }
#pragma unroll
        for (int j = 0; j < 8; j++) kf[j] = kn[j];
    }

#pragma unroll
    for (int i = 0; i < 4; i++) {
        const float li = __shfl(l_run, srcb + i, 64);
        const float inv = 1.0f / fmaxf(li, 1e-30f);
        const size_t row = rowb + q0 + 4 * g + i;
#pragma unroll
        for (int n = 0; n < 4; n++)
            O[row * 768 + h * 64 + n * 16 + c] = f2bf(o_acc[n][i] * inv);
    }
}

// ---------------------------------------------------------------------------
// Launch
// ---------------------------------------------------------------------------
extern "C" void kernel_launch(void* const* d_in, const int* in_sizes, int n_in,
                              void* d_out, int out_size, void* d_ws, size_t ws_size,
                              hipStream_t stream)
{
    const float* x   = (const float*)d_in[0];
    const float* wq  = (const float*)d_in[1];
    const float* bq  = (const float*)d_in[2];
    const float* wk  = (const float*)d_in[3];
    const float* bk  = (const float*)d_in[4];
    const float* wv  = (const float*)d_in[5];
    const float* bv  = (const float*)d_in[6];
    const float* wo  = (const float*)d_in[7];
    const float* bo  = (const float*)d_in[8];
    const float* w1  = (const float*)d_in[9];
    const float* b1  = (const float*)d_in[10];
    const float* w2  = (const float*)d_in[11];
    const float* b2  = (const float*)d_in[12];
    const float* g1  = (const float*)d_in[13];
    const float* be1 = (const float*)d_in[14];
    const float* g2  = (const float*)d_in[15];
    const float* be2 = (const float*)d_in[16];

    char* ws = (char*)d_ws;
    constexpr size_t O_WQKV = 0;                       // [2304][768] bf16
    constexpr size_t O_WO   = 3538944;                 // [768][768]  bf16
    constexpr size_t O_W1   = 4718592;                 // [3072][768] bf16
    constexpr size_t O_W2   = 9437184;                 // [768][3072] bf16
    constexpr size_t O_BQKV = 14155776;                // [2304] f32
    constexpr size_t O_XLN  = 14168064;                // [8192][768] bf16
    constexpr size_t O_Q    = O_XLN + 12582912;
    constexpr size_t O_K    = O_Q + 12582912;
    constexpr size_t O_VT   = O_K + 12582912;          // [96][64][1024] bf16
    constexpr size_t O_ATTN = O_VT + 12582912;
    constexpr size_t O_H    = O_ATTN + 12582912;       // [8192][768] f32
    constexpr size_t O_F    = O_XLN;                   // overlays xln..VT
    constexpr size_t O_HLN  = O_ATTN;                  // overlays attnb

    u16* wqkvT = (u16*)(ws + O_WQKV);
    u16* woT   = (u16*)(ws + O_WO);
    u16* w1T   = (u16*)(ws + O_W1);
    u16* w2T   = (u16*)(ws + O_W2);
    float* bqkv = (float*)(ws + O_BQKV);
    u16* xln   = (u16*)(ws + O_XLN);
    u16* Qb    = (u16*)(ws + O_Q);
    u16* Kb    = (u16*)(ws + O_K);
    u16* VTg   = (u16*)(ws + O_VT);
    u16* attnb = (u16*)(ws + O_ATTN);
    float* h   = (float*)(ws + O_H);
    u16* fb    = (u16*)(ws + O_F);
    u16* hln   = (u16*)(ws + O_HLN);

    dim3 blk(256);
    prep_kernel<<<6921, blk, 0, stream>>>(wq, wk, wv, wo, w1, w2, bq, bk, bv,
                                          wqkvT, woT, w1T, w2T, bqkv);
    ln_kernel<<<8192, blk, 0, stream>>>(x, xln, g1, be1);
    gemm_kernel<MODE_QKV><<<dim3(64, 18), blk, 0, stream>>>(
        xln, wqkvT, bqkv, nullptr, Qb, Kb, VTg, 8192, 2304, 768);
    attn_kernel<<<1536, blk, 0, stream>>>(Qb, Kb, VTg, attnb);
    gemm_kernel<MODE_RESF32><<<dim3(64, 6), blk, 0, stream>>>(
        attnb, woT, bo, x, h, nullptr, nullptr, 8192, 768, 768);
    ln_kernel<<<8192, blk, 0, stream>>>(h, hln, g2, be2);
    gemm_kernel<MODE_GELU><<<dim3(64, 24), blk, 0, stream>>>(
        hln, w1T, b1, nullptr, fb, nullptr, nullptr, 8192, 3072, 768);
    gemm_kernel<MODE_RESF32><<<dim3(64, 6), blk, 0, stream>>>(
        fb, w2T, b2, h, (float*)d_out, nullptr, nullptr, 8192, 768, 3072);
}

// Round 7
// 330.737 us; speedup vs baseline: 1.3207x; 1.3207x over previous
//
#include <hip/hip_runtime.h>
#include <hip/hip_bf16.h>
#include <math.h>

typedef unsigned short u16;
typedef unsigned int u32;
typedef u16 u16x8 __attribute__((ext_vector_type(8)));
typedef __bf16 bf16x8 __attribute__((ext_vector_type(8)));
typedef float f32x4 __attribute__((ext_vector_type(4)));

#define MODE_GELU 1
#define MODE_RESF32 2
#define MODE_QKV 3

template <typename T, typename F>
__device__ __forceinline__ T bitcast(F f) { return __builtin_bit_cast(T, f); }

__device__ __forceinline__ u16 f2bf(float f) {
    unsigned int u = __float_as_uint(f);
    u = (u + 0x7fffu + ((u >> 16) & 1u)) >> 16;
    return (u16)u;
}

__device__ __forceinline__ u32 packbf(float lo, float hi) {
    return (u32)f2bf(lo) | ((u32)f2bf(hi) << 16);
}

__device__ __forceinline__ void gl_lds16(const u16* g, u16* l) {
    __builtin_amdgcn_global_load_lds(
        (const __attribute__((address_space(1))) unsigned int*)(const void*)g,
        (__attribute__((address_space(3))) unsigned int*)(void*)l,
        16, 0, 0);
}

// Stage a 64-row x 64-col (u16) tile into LDS, XOR-swizzling the SOURCE so a
// later read of (row, slot^f(row)) returns logical (row, slot). f spreads the
// 8 16B-slots of a row; linear LDS dest (global_load_lds requirement).
__device__ __forceinline__ void stage64(const u16* __restrict__ src, int stride,
                                        u16* __restrict__ lds, int t)
{
    const int wave = t >> 6, lane = t & 63;
#pragma unroll
    for (int i = 0; i < 2; i++) {
        const int row = i * 32 + wave * 8 + (lane >> 3);
        const int s = lane & 7;
        const int f = (((row >> 3) & 1) << 2) | (row & 3);
        gl_lds16(src + (size_t)row * stride + (size_t)((s ^ f) << 3),
                 lds + i * 2048 + wave * 512);
    }
}

// ---------------------------------------------------------------------------
// prep: all 6 weight transposes (W[K][N] -> WT[N][K] bf16) + bias concat.
// ---------------------------------------------------------------------------
__global__ __launch_bounds__(256) void prep_kernel(
    const float* __restrict__ wq, const float* __restrict__ wk,
    const float* __restrict__ wv, const float* __restrict__ wo,
    const float* __restrict__ w1, const float* __restrict__ w2,
    const float* __restrict__ bq, const float* __restrict__ bk,
    const float* __restrict__ bv,
    u16* __restrict__ wqkvT, u16* __restrict__ woT,
    u16* __restrict__ w1T, u16* __restrict__ w2T, float* __restrict__ bqkv)
{
    const int blk = blockIdx.x;
    if (blk >= 6912) {
        const int t = (blk - 6912) * 256 + threadIdx.x;
        if (t < 2304)
            bqkv[t] = t < 768 ? bq[t] : (t < 1536 ? bk[t - 768] : bv[t - 1536]);
        return;
    }
    const float* W; u16* WT; int Krows, Ncols, lt;
    if (blk < 576)       { W = wq; WT = wqkvT;                       Krows = 768;  Ncols = 768;  lt = blk; }
    else if (blk < 1152) { W = wk; WT = wqkvT + (size_t)768 * 768;   Krows = 768;  Ncols = 768;  lt = blk - 576; }
    else if (blk < 1728) { W = wv; WT = wqkvT + (size_t)1536 * 768;  Krows = 768;  Ncols = 768;  lt = blk - 1152; }
    else if (blk < 2304) { W = wo; WT = woT;                         Krows = 768;  Ncols = 768;  lt = blk - 1728; }
    else if (blk < 4608) { W = w1; WT = w1T;                         Krows = 768;  Ncols = 3072; lt = blk - 2304; }
    else                 { W = w2; WT = w2T;                         Krows = 3072; Ncols = 768;  lt = blk - 4608; }
    const int ktiles = Krows >> 5;
    const int k0 = (lt % ktiles) * 32, n0 = (lt / ktiles) * 32;

    __shared__ float tile[32][33];
    const int tx = threadIdx.x & 31, ty = threadIdx.x >> 5;
#pragma unroll
    for (int j = 0; j < 32; j += 8)
        tile[ty + j][tx] = W[(size_t)(k0 + ty + j) * Ncols + n0 + tx];
    __syncthreads();
#pragma unroll
    for (int j = 0; j < 32; j += 8)
        WT[(size_t)(n0 + ty + j) * Krows + k0 + tx] = f2bf(tile[tx][ty + j]);
}

// ---------------------------------------------------------------------------
// LayerNorm (ddof=1, divide by std+eps, scalar gamma/beta), fp32 -> bf16
// ---------------------------------------------------------------------------
__global__ __launch_bounds__(256) void ln_kernel(
    const float* __restrict__ X, u16* __restrict__ Y,
    const float* __restrict__ gp, const float* __restrict__ bp)
{
    __shared__ float sbuf[8];
    const int row = blockIdx.x, t = threadIdx.x;
    const float* xr = X + (size_t)row * 768;
    float v0 = xr[t], v1 = xr[t + 256], v2 = xr[t + 512];
    float s = v0 + v1 + v2;
    float q = v0 * v0 + v1 * v1 + v2 * v2;
#pragma unroll
    for (int m = 1; m < 64; m <<= 1) {
        s += __shfl_xor(s, m, 64);
        q += __shfl_xor(q, m, 64);
    }
    const int wave = t >> 6, lane = t & 63;
    if (lane == 0) { sbuf[wave] = s; sbuf[4 + wave] = q; }
    __syncthreads();
    s = sbuf[0] + sbuf[1] + sbuf[2] + sbuf[3];
    q = sbuf[4] + sbuf[5] + sbuf[6] + sbuf[7];
    const float mean = s * (1.0f / 768.0f);
    float ssd = q - 768.0f * mean * mean;
    ssd = fmaxf(ssd, 0.0f);
    const float stdv = sqrtf(ssd * (1.0f / 767.0f));
    const float scale = gp[0] / (stdv + 1e-5f);
    const float beta = bp[0];
    u16* yr = Y + (size_t)row * 768;
    yr[t]       = f2bf((v0 - mean) * scale + beta);
    yr[t + 256] = f2bf((v1 - mean) * scale + beta);
    yr[t + 512] = f2bf((v2 - mean) * scale + beta);
}

// ---------------------------------------------------------------------------
// GEMM (m97 structure): C[M][N] = A @ BT^T + bias, global_load_lds staging.
// ---------------------------------------------------------------------------
template <int MODE>
__global__ __launch_bounds__(256) void gemm_kernel(
    const u16* __restrict__ A, const u16* __restrict__ BT,
    const float* __restrict__ bias, const float* __restrict__ res,
    void* __restrict__ out0, void* __restrict__ out1, void* __restrict__ out2,
    int M, int N, int K)
{
    __shared__ u16 sh[2 * 128 * 64];          // As | Bs; reused for V-transpose
    u16* Asb = sh;
    u16* Bsb = sh + 8192;
    const int t = threadIdx.x;
    const int lane = t & 63, wave = t >> 6;
    const int wr = wave >> 1, wc = wave & 1;
    const int g = lane >> 4, c = lane & 15;
    const int bm = blockIdx.x, bn = blockIdx.y;

    const int srow = wave * 32 + (lane >> 3);
    const int scol = (lane & 7) * 8;
    const u16* Ag = A + (size_t)(bm * 128 + srow) * K + scol;
    const u16* Bg = BT + (size_t)(bn * 128 + srow) * K + scol;
    u16* AsW = Asb + wave * 2048;
    u16* BsW = Bsb + wave * 2048;

    f32x4 acc[4][4] = {};

    for (int k0 = 0; k0 < K; k0 += 64) {
        __syncthreads();
#pragma unroll
        for (int it = 0; it < 4; it++) {
            gl_lds16(Ag + (size_t)(it * 8) * K + k0, AsW + it * 512);
            gl_lds16(Bg + (size_t)(it * 8) * K + k0, BsW + it * 512);
        }
        __syncthreads();
#pragma unroll
        for (int kk = 0; kk < 2; kk++) {
            bf16x8 af[4], bfr[4];
#pragma unroll
            for (int m = 0; m < 4; m++)
                af[m] = *(const bf16x8*)&Asb[(wr * 64 + m * 16 + c) * 64 + kk * 32 + g * 8];
#pragma unroll
            for (int n = 0; n < 4; n++)
                bfr[n] = *(const bf16x8*)&Bsb[(wc * 64 + n * 16 + c) * 64 + kk * 32 + g * 8];
#pragma unroll
            for (int m = 0; m < 4; m++)
#pragma unroll
                for (int n = 0; n < 4; n++)
                    acc[m][n] = __builtin_amdgcn_mfma_f32_16x16x32_bf16(
                        af[m], bfr[n], acc[m][n], 0, 0, 0);
        }
    }

    if constexpr (MODE == MODE_QKV) {
        if (bn >= 12) {
            // ---- V section: LDS tile transpose, coalesced V^T stores ----
            __syncthreads();
#pragma unroll
            for (int m = 0; m < 4; m++) {
#pragma unroll
                for (int n = 0; n < 4; n++) {
                    const int colL = wc * 64 + n * 16 + c;
                    const int rowLb = wr * 64 + m * 16 + 4 * g;
                    const float bv = bias[bn * 128 + colL];
                    const u32 x0 = packbf(acc[m][n][0] + bv, acc[m][n][1] + bv);
                    const u32 x1 = packbf(acc[m][n][2] + bv, acc[m][n][3] + bv);
                    const int elem = colL * 128 + (rowLb ^ ((colL & 15) << 3));
                    ((u32*)sh)[elem >> 1] = x0;
                    ((u32*)sh)[(elem >> 1) + 1] = x1;
                }
            }
            __syncthreads();
            const int bn_off = bn - 12;
            const int bb = bm >> 3, kvb = (bm & 7) * 128;
            const int j8 = (t & 7) * 8;
#pragma unroll
            for (int it = 0; it < 4; it++) {
                const int colL2 = it * 32 + (t >> 3);
                const int gcol = bn_off * 128 + colL2;
                const int hh = gcol >> 6, d = gcol & 63;
                const size_t obase = ((size_t)(bb * 12 + hh) << 16) + ((size_t)d << 10) + kvb;
                const int X = (colL2 & 15) << 3;
#pragma unroll
                for (int half = 0; half < 2; half++) {
                    const int rowL2 = half * 64 + j8;
                    const int elem = colL2 * 128 + (rowL2 ^ X);
                    *(u16x8*)((u16*)out2 + obase + rowL2) = *(const u16x8*)&sh[elem];
                }
            }
            return;
        }
    }

#pragma unroll
    for (int m = 0; m < 4; m++) {
        const int row = bm * 128 + wr * 64 + m * 16 + 4 * g;
#pragma unroll
        for (int n = 0; n < 4; n++) {
            const int col = bn * 128 + wc * 64 + n * 16 + c;
            const float bv = bias[col];
#pragma unroll
            for (int i = 0; i < 4; i++) {
                float v = acc[m][n][i] + bv;
                if constexpr (MODE == MODE_GELU) {
                    v = 0.5f * v * (1.0f + erff(v * 0.70710678118654752f));
                    ((u16*)out0)[(size_t)(row + i) * N + col] = f2bf(v);
                } else if constexpr (MODE == MODE_RESF32) {
                    const size_t idx = (size_t)(row + i) * N + col;
                    ((float*)out0)[idx] = v + res[idx];
                } else {
                    const int sect = (col >= 768) ? 1 : 0;
                    const int colm = col - sect * 768;
                    u16* dst = sect ? (u16*)out1 : (u16*)out0;
                    dst[(size_t)(row + i) * 768 + colm] = f2bf(v);
                }
            }
        }
    }
}

// ---------------------------------------------------------------------------
// Flash attention v3: swapped QK^T, in-register softmax, LDS-staged K+V with
// swizzled-source double-buffered global_load_lds staging (1 barrier/tile).
// grid 768 linear; XCD-aware head mapping (12 heads per XCD, K+V L2-resident).
// 256 thr = 4 waves x 32 q-rows (2 groups of 16); KV tile 64.
// Each ds_read fragment feeds BOTH q-groups (2x arithmetic intensity).
// ---------------------------------------------------------------------------
__global__ __launch_bounds__(256) void attn_kernel(
    const u16* __restrict__ Qg, const u16* __restrict__ Kg,
    const u16* __restrict__ Vt_g, u16* __restrict__ O)
{
    __shared__ u16 Kl[2][4096];
    __shared__ u16 Vl[2][4096];
    const int t = threadIdx.x, lane = t & 63, wave = t >> 6;
    const int g = lane >> 4, c = lane & 15;
    const int l = blockIdx.x;
    const int pos = l >> 3;
    const int bh = (l & 7) * 12 + (pos >> 3);
    const int qt = pos & 7;
    const int b = bh / 12, h = bh % 12;
    const size_t rowb = (size_t)b * 1024;
    const int q0 = qt * 128 + wave * 32;

    // Q fragments for 2 q-groups (rows q0+c and q0+16+c), exp2-unit scaled
    bf16x8 qa[2], qb[2];
    {
        const u16* qp = Qg + (rowb + q0 + c) * 768 + h * 64 + g * 8;
        u16x8 a0 = *(const u16x8*)qp;
        u16x8 a1 = *(const u16x8*)(qp + 32);
        u16x8 b0 = *(const u16x8*)(qp + 16 * 768);
        u16x8 b1 = *(const u16x8*)(qp + 16 * 768 + 32);
        bf16x8 va0, va1, vb0, vb1;
#pragma unroll
        for (int j = 0; j < 8; j++) {
            const float SC = 0.18033688011112042f;   // 0.125 * log2(e)
            va0[j] = (__bf16)(__uint_as_float(((u32)a0[j]) << 16) * SC);
            va1[j] = (__bf16)(__uint_as_float(((u32)a1[j]) << 16) * SC);
            vb0[j] = (__bf16)(__uint_as_float(((u32)b0[j]) << 16) * SC);
            vb1[j] = (__bf16)(__uint_as_float(((u32)b1[j]) << 16) * SC);
        }
        qa[0] = va0; qa[1] = va1; qb[0] = vb0; qb[1] = vb1;
    }

    // K fragment row constants (permuted so P lands in the PV A-fragment) and
    // per-row read-XOR values matching stage64's source swizzle.
    int kro[4], kxo[4], vro[4];
#pragma unroll
    for (int n = 0; n < 4; n++) {
        const int pr = ((n >> 1) << 5) + ((c >> 2) << 3) + ((n & 1) << 2) + (c & 3);
        kro[n] = pr << 6;
        kxo[n] = (((pr >> 3) & 1) << 2) | (pr & 3);
        vro[n] = (n * 16 + c) << 6;
    }
    const int vxo = (((c >> 3) & 1) << 2) | (c & 3);

    const u16* ksrc = Kg + rowb * 768 + h * 64;
    const u16* vsrc = Vt_g + (size_t)bh * 65536;

    float m0 = -1e30f, l0 = 0.f, m1 = -1e30f, l1 = 0.f;
    f32x4 oa[4] = {}, ob[4] = {};
    const int srcb = (lane & 48) | ((lane >> 2) & 12);

    stage64(ksrc, 768, Kl[0], t);
    stage64(vsrc, 1024, Vl[0], t);
    __syncthreads();

    for (int kvt = 0; kvt < 16; ++kvt) {
        const u16* Kc = Kl[kvt & 1];
        const u16* Vc = Vl[kvt & 1];
        if (kvt < 15) {   // stage next tile; latency hides under this tile's math
            stage64(ksrc + (size_t)(kvt + 1) * 64 * 768, 768, Kl[(kvt + 1) & 1], t);
            stage64(vsrc + (kvt + 1) * 64, 1024, Vl[(kvt + 1) & 1], t);
        }

        // QK^T for both q-groups; each K fragment feeds 2 MFMAs
        f32x4 s0[4] = {}, s1[4] = {};
#pragma unroll
        for (int n = 0; n < 4; n++) {
#pragma unroll
            for (int kk = 0; kk < 2; kk++) {
                const bf16x8 kf = *(const bf16x8*)&Kc[kro[n] + ((((kk << 2) + g) ^ kxo[n]) << 3)];
                s0[n] = __builtin_amdgcn_mfma_f32_16x16x32_bf16(kf, qa[kk], s0[n], 0, 0, 0);
                s1[n] = __builtin_amdgcn_mfma_f32_16x16x32_bf16(kf, qb[kk], s1[n], 0, 0, 0);
            }
        }

        // ---- softmax group 0 ----
        bf16x8 pa00, pa01;
        {
            float t0 = fmaxf(fmaxf(s0[0][0], s0[0][1]), fmaxf(s0[0][2], s0[0][3]));
            float t1 = fmaxf(fmaxf(s0[1][0], s0[1][1]), fmaxf(s0[1][2], s0[1][3]));
            float t2 = fmaxf(fmaxf(s0[2][0], s0[2][1]), fmaxf(s0[2][2], s0[2][3]));
            float t3 = fmaxf(fmaxf(s0[3][0], s0[3][1]), fmaxf(s0[3][2], s0[3][3]));
            float mx = fmaxf(fmaxf(t0, t1), fmaxf(t2, t3));
            mx = fmaxf(mx, __shfl_xor(mx, 16, 64));
            mx = fmaxf(mx, __shfl_xor(mx, 32, 64));
            if (!__all(mx <= m0 + 8.0f)) {
                const float mn = fmaxf(m0, mx);
                const float rsc = exp2f(m0 - mn);
                m0 = mn; l0 *= rsc;
                f32x4 rq;
#pragma unroll
                for (int i = 0; i < 4; i++) rq[i] = __shfl(rsc, srcb + i, 64);
#pragma unroll
                for (int n = 0; n < 4; n++) oa[n] *= rq;
            }
            float r = 0.f;
#pragma unroll
            for (int n = 0; n < 4; n++)
#pragma unroll
                for (int i = 0; i < 4; i++) {
                    s0[n][i] = exp2f(s0[n][i] - m0);
                    r += s0[n][i];
                }
            r += __shfl_xor(r, 16, 64);
            r += __shfl_xor(r, 32, 64);
            l0 += r;
#pragma unroll
            for (int i = 0; i < 4; i++) {
                pa00[i] = (__bf16)s0[0][i]; pa00[4 + i] = (__bf16)s0[1][i];
                pa01[i] = (__bf16)s0[2][i]; pa01[4 + i] = (__bf16)s0[3][i];
            }
        }
        // ---- softmax group 1 ----
        bf16x8 pa10, pa11;
        {
            float t0 = fmaxf(fmaxf(s1[0][0], s1[0][1]), fmaxf(s1[0][2], s1[0][3]));
            float t1 = fmaxf(fmaxf(s1[1][0], s1[1][1]), fmaxf(s1[1][2], s1[1][3]));
            float t2 = fmaxf(fmaxf(s1[2][0], s1[2][1]), fmaxf(s1[2][2], s1[2][3]));
            float t3 = fmaxf(fmaxf(s1[3][0], s1[3][1]), fmaxf(s1[3][2], s1[3][3]));
            float mx = fmaxf(fmaxf(t0, t1), fmaxf(t2, t3));
            mx = fmaxf(mx, __shfl_xor(mx, 16, 64));
            mx = fmaxf(mx, __shfl_xor(mx, 32, 64));
            if (!__all(mx <= m1 + 8.0f)) {
                const float mn = fmaxf(m1, mx);
                const float rsc = exp2f(m1 - mn);
                m1 = mn; l1 *= rsc;
                f32x4 rq;
#pragma unroll
                for (int i = 0; i < 4; i++) rq[i] = __shfl(rsc, srcb + i, 64);
#pragma unroll
                for (int n = 0; n < 4; n++) ob[n] *= rq;
            }
            float r = 0.f;
#pragma unroll
            for (int n = 0; n < 4; n++)
#pragma unroll
                for (int i = 0; i < 4; i++) {
                    s1[n][i] = exp2f(s1[n][i] - m1);
                    r += s1[n][i];
                }
            r += __shfl_xor(r, 16, 64);
            r += __shfl_xor(r, 32, 64);
            l1 += r;
#pragma unroll
            for (int i = 0; i < 4; i++) {
                pa10[i] = (__bf16)s1[0][i]; pa10[4 + i] = (__bf16)s1[1][i];
                pa11[i] = (__bf16)s1[2][i]; pa11[4 + i] = (__bf16)s1[3][i];
            }
        }

        // PV for both q-groups; each V fragment feeds 2 MFMAs
#pragma unroll
        for (int n = 0; n < 4; n++) {
#pragma unroll
            for (int kk = 0; kk < 2; kk++) {
                const bf16x8 vf = *(const bf16x8*)&Vc[vro[n] + ((((kk << 2) + g) ^ vxo) << 3)];
                oa[n] = __builtin_amdgcn_mfma_f32_16x16x32_bf16(kk ? pa01 : pa00, vf, oa[n], 0, 0, 0);
                ob[n] = __builtin_amdgcn_mfma_f32_16x16x32_bf16(kk ? pa11 : pa10, vf, ob[n], 0, 0, 0);
            }
        }
        __syncthreads();   // all waves done with cur; next tile's stage landed
    }

#pragma unroll
    for (int i = 0; i < 4; i++) {
        const float la = __shfl(l0, srcb + i, 64);
        const float lb = __shfl(l1, srcb + i, 64);
        const float ia_ = 1.0f / fmaxf(la, 1e-30f);
        const float ib_ = 1.0f / fmaxf(lb, 1e-30f);
        const size_t ra_ = rowb + q0 + 4 * g + i;
#pragma unroll
        for (int n = 0; n < 4; n++) {
            O[ra_ * 768 + h * 64 + n * 16 + c]        = f2bf(oa[n][i] * ia_);
            O[(ra_ + 16) * 768 + h * 64 + n * 16 + c] = f2bf(ob[n][i] * ib_);
        }
    }
}

// ---------------------------------------------------------------------------
// Launch
// ---------------------------------------------------------------------------
extern "C" void kernel_launch(void* const* d_in, const int* in_sizes, int n_in,
                              void* d_out, int out_size, void* d_ws, size_t ws_size,
                              hipStream_t stream)
{
    const float* x   = (const float*)d_in[0];
    const float* wq  = (const float*)d_in[1];
    const float* bq  = (const float*)d_in[2];
    const float* wk  = (const float*)d_in[3];
    const float* bk  = (const float*)d_in[4];
    const float* wv  = (const float*)d_in[5];
    const float* bv  = (const float*)d_in[6];
    const float* wo  = (const float*)d_in[7];
    const float* bo  = (const float*)d_in[8];
    const float* w1  = (const float*)d_in[9];
    const float* b1  = (const float*)d_in[10];
    const float* w2  = (const float*)d_in[11];
    const float* b2  = (const float*)d_in[12];
    const float* g1  = (const float*)d_in[13];
    const float* be1 = (const float*)d_in[14];
    const float* g2  = (const float*)d_in[15];
    const float* be2 = (const float*)d_in[16];

    char* ws = (char*)d_ws;
    constexpr size_t O_WQKV = 0;                       // [2304][768] bf16
    constexpr size_t O_WO   = 3538944;                 // [768][768]  bf16
    constexpr size_t O_W1   = 4718592;                 // [3072][768] bf16
    constexpr size_t O_W2   = 9437184;                 // [768][3072] bf16
    constexpr size_t O_BQKV = 14155776;                // [2304] f32
    constexpr size_t O_XLN  = 14168064;                // [8192][768] bf16
    constexpr size_t O_Q    = O_XLN + 12582912;
    constexpr size_t O_K    = O_Q + 12582912;
    constexpr size_t O_VT   = O_K + 12582912;          // [96][64][1024] bf16
    constexpr size_t O_ATTN = O_VT + 12582912;
    constexpr size_t O_H    = O_ATTN + 12582912;       // [8192][768] f32
    constexpr size_t O_F    = O_XLN;                   // overlays xln..VT
    constexpr size_t O_HLN  = O_ATTN;                  // overlays attnb

    u16* wqkvT = (u16*)(ws + O_WQKV);
    u16* woT   = (u16*)(ws + O_WO);
    u16* w1T   = (u16*)(ws + O_W1);
    u16* w2T   = (u16*)(ws + O_W2);
    float* bqkv = (float*)(ws + O_BQKV);
    u16* xln   = (u16*)(ws + O_XLN);
    u16* Qb    = (u16*)(ws + O_Q);
    u16* Kb    = (u16*)(ws + O_K);
    u16* VTg   = (u16*)(ws + O_VT);
    u16* attnb = (u16*)(ws + O_ATTN);
    float* h   = (float*)(ws + O_H);
    u16* fb    = (u16*)(ws + O_F);
    u16* hln   = (u16*)(ws + O_HLN);

    dim3 blk(256);
    prep_kernel<<<6921, blk, 0, stream>>>(wq, wk, wv, wo, w1, w2, bq, bk, bv,
                                          wqkvT, woT, w1T, w2T, bqkv);
    ln_kernel<<<8192, blk, 0, stream>>>(x, xln, g1, be1);
    gemm_kernel<MODE_QKV><<<dim3(64, 18), blk, 0, stream>>>(
        xln, wqkvT, bqkv, nullptr, Qb, Kb, VTg, 8192, 2304, 768);
    attn_kernel<<<768, blk, 0, stream>>>(Qb, Kb, VTg, attnb);
    gemm_kernel<MODE_RESF32><<<dim3(64, 6), blk, 0, stream>>>(
        attnb, woT, bo, x, h, nullptr, nullptr, 8192, 768, 768);
    ln_kernel<<<8192, blk, 0, stream>>>(h, hln, g2, be2);
    gemm_kernel<MODE_GELU><<<dim3(64, 24), blk, 0, stream>>>(
        hln, w1T, b1, nullptr, fb, nullptr, nullptr, 8192, 3072, 768);
    gemm_kernel<MODE_RESF32><<<dim3(64, 6), blk, 0, stream>>>(
        fb, w2T, b2, h, (float*)d_out, nullptr, nullptr, 8192, 768, 3072);
}

// Round 8
// 277.276 us; speedup vs baseline: 1.5754x; 1.1928x over previous
//
#include <hip/hip_runtime.h>
#include <hip/hip_bf16.h>
#include <math.h>

typedef unsigned short u16;
typedef unsigned int u32;
typedef u16 u16x8 __attribute__((ext_vector_type(8)));
typedef __bf16 bf16x8 __attribute__((ext_vector_type(8)));
typedef float f32x4 __attribute__((ext_vector_type(4)));

#define MODE_GELU 1
#define MODE_RESF32 2
#define MODE_QKV 3

template <typename T, typename F>
__device__ __forceinline__ T bitcast(F f) { return __builtin_bit_cast(T, f); }

__device__ __forceinline__ u16 f2bf(float f) {
    unsigned int u = __float_as_uint(f);
    u = (u + 0x7fffu + ((u >> 16) & 1u)) >> 16;
    return (u16)u;
}

__device__ __forceinline__ u32 packbf(float lo, float hi) {
    return (u32)f2bf(lo) | ((u32)f2bf(hi) << 16);
}

// branch-free GELU: x * sigmoid(1.5957691(x + 0.044715 x^3)); max |err| vs
// exact-erf GELU ~3e-3 (<< 0.1256 threshold). Native v_exp_f32 + v_rcp_f32.
__device__ __forceinline__ float fast_gelu(float x) {
    const float arg = x * (2.30220775f + 0.10294329f * x * x);  // 2y*log2(e)
    const float e = exp2f(arg);                                  // e^{2y}
    return x * (1.0f - __builtin_amdgcn_rcpf(e + 1.0f));
}

__device__ __forceinline__ void gl_lds16(const u16* g, u16* l) {
    __builtin_amdgcn_global_load_lds(
        (const __attribute__((address_space(1))) unsigned int*)(const void*)g,
        (__attribute__((address_space(3))) unsigned int*)(void*)l,
        16, 0, 0);
}

// Stage a 64-row x 64-col (u16) tile into LDS, XOR-swizzling the SOURCE so a
// later read of (row, slot^f(row)) returns logical (row, slot).
__device__ __forceinline__ void stage64(const u16* __restrict__ src, int stride,
                                        u16* __restrict__ lds, int t)
{
    const int wave = t >> 6, lane = t & 63;
#pragma unroll
    for (int i = 0; i < 2; i++) {
        const int row = i * 32 + wave * 8 + (lane >> 3);
        const int s = lane & 7;
        const int f = (((row >> 3) & 1) << 2) | (row & 3);
        gl_lds16(src + (size_t)row * stride + (size_t)((s ^ f) << 3),
                 lds + i * 2048 + wave * 512);
    }
}

// ---------------------------------------------------------------------------
// prep: all 6 weight transposes (W[K][N] -> WT[N][K] bf16) + bias concat.
// ---------------------------------------------------------------------------
__global__ __launch_bounds__(256) void prep_kernel(
    const float* __restrict__ wq, const float* __restrict__ wk,
    const float* __restrict__ wv, const float* __restrict__ wo,
    const float* __restrict__ w1, const float* __restrict__ w2,
    const float* __restrict__ bq, const float* __restrict__ bk,
    const float* __restrict__ bv,
    u16* __restrict__ wqkvT, u16* __restrict__ woT,
    u16* __restrict__ w1T, u16* __restrict__ w2T, float* __restrict__ bqkv)
{
    const int blk = blockIdx.x;
    if (blk >= 6912) {
        const int t = (blk - 6912) * 256 + threadIdx.x;
        if (t < 2304)
            bqkv[t] = t < 768 ? bq[t] : (t < 1536 ? bk[t - 768] : bv[t - 1536]);
        return;
    }
    const float* W; u16* WT; int Krows, Ncols, lt;
    if (blk < 576)       { W = wq; WT = wqkvT;                       Krows = 768;  Ncols = 768;  lt = blk; }
    else if (blk < 1152) { W = wk; WT = wqkvT + (size_t)768 * 768;   Krows = 768;  Ncols = 768;  lt = blk - 576; }
    else if (blk < 1728) { W = wv; WT = wqkvT + (size_t)1536 * 768;  Krows = 768;  Ncols = 768;  lt = blk - 1152; }
    else if (blk < 2304) { W = wo; WT = woT;                         Krows = 768;  Ncols = 768;  lt = blk - 1728; }
    else if (blk < 4608) { W = w1; WT = w1T;                         Krows = 768;  Ncols = 3072; lt = blk - 2304; }
    else                 { W = w2; WT = w2T;                         Krows = 3072; Ncols = 768;  lt = blk - 4608; }
    const int ktiles = Krows >> 5;
    const int k0 = (lt % ktiles) * 32, n0 = (lt / ktiles) * 32;

    __shared__ float tile[32][33];
    const int tx = threadIdx.x & 31, ty = threadIdx.x >> 5;
#pragma unroll
    for (int j = 0; j < 32; j += 8)
        tile[ty + j][tx] = W[(size_t)(k0 + ty + j) * Ncols + n0 + tx];
    __syncthreads();
#pragma unroll
    for (int j = 0; j < 32; j += 8)
        WT[(size_t)(n0 + ty + j) * Krows + k0 + tx] = f2bf(tile[tx][ty + j]);
}

// ---------------------------------------------------------------------------
// LayerNorm (ddof=1, divide by std+eps, scalar gamma/beta), fp32 -> bf16
// ---------------------------------------------------------------------------
__global__ __launch_bounds__(256) void ln_kernel(
    const float* __restrict__ X, u16* __restrict__ Y,
    const float* __restrict__ gp, const float* __restrict__ bp)
{
    __shared__ float sbuf[8];
    const int row = blockIdx.x, t = threadIdx.x;
    const float* xr = X + (size_t)row * 768;
    float v0 = xr[t], v1 = xr[t + 256], v2 = xr[t + 512];
    float s = v0 + v1 + v2;
    float q = v0 * v0 + v1 * v1 + v2 * v2;
#pragma unroll
    for (int m = 1; m < 64; m <<= 1) {
        s += __shfl_xor(s, m, 64);
        q += __shfl_xor(q, m, 64);
    }
    const int wave = t >> 6, lane = t & 63;
    if (lane == 0) { sbuf[wave] = s; sbuf[4 + wave] = q; }
    __syncthreads();
    s = sbuf[0] + sbuf[1] + sbuf[2] + sbuf[3];
    q = sbuf[4] + sbuf[5] + sbuf[6] + sbuf[7];
    const float mean = s * (1.0f / 768.0f);
    float ssd = q - 768.0f * mean * mean;
    ssd = fmaxf(ssd, 0.0f);
    const float stdv = sqrtf(ssd * (1.0f / 767.0f));
    const float scale = gp[0] / (stdv + 1e-5f);
    const float beta = bp[0];
    u16* yr = Y + (size_t)row * 768;
    yr[t]       = f2bf((v0 - mean) * scale + beta);
    yr[t + 256] = f2bf((v1 - mean) * scale + beta);
    yr[t + 512] = f2bf((v2 - mean) * scale + beta);
}

// ---------------------------------------------------------------------------
// GEMM v2: 2-phase double-buffered pipeline (T3-minimum recipe).
// STAGE(next) -> ds_read/MFMA(cur) -> one barrier per K-step.
// 128x128 tile, BK=64, 256 thr = 4 waves (2x2), LDS 64 KB (2 x A|B).
// ---------------------------------------------------------------------------
template <int MODE>
__global__ __launch_bounds__(256) void gemm_kernel(
    const u16* __restrict__ A, const u16* __restrict__ BT,
    const float* __restrict__ bias, const float* __restrict__ res,
    void* __restrict__ out0, void* __restrict__ out1, void* __restrict__ out2,
    int M, int N, int K)
{
    __shared__ u16 sh[2][2][128 * 64];        // [dbuf][A|B]; reused for V-transpose
    u16* shp = &sh[0][0][0];
    const int t = threadIdx.x;
    const int lane = t & 63, wave = t >> 6;
    const int wr = wave >> 1, wc = wave & 1;
    const int g = lane >> 4, c = lane & 15;
    const int bm = blockIdx.x, bn = blockIdx.y;

    const int srow = wave * 32 + (lane >> 3);
    const int scol = (lane & 7) * 8;
    const u16* Ag = A + (size_t)(bm * 128 + srow) * K + scol;
    const u16* Bg = BT + (size_t)(bn * 128 + srow) * K + scol;

    f32x4 acc[4][4] = {};
    const int nk = K >> 6;

#define STAGE_AB(buf, k0)                                                     \
    {                                                                         \
        _Pragma("unroll")                                                     \
        for (int it = 0; it < 4; it++) {                                      \
            gl_lds16(Ag + (size_t)(it * 8) * K + (k0), &sh[buf][0][wave * 2048 + it * 512]); \
            gl_lds16(Bg + (size_t)(it * 8) * K + (k0), &sh[buf][1][wave * 2048 + it * 512]); \
        }                                                                     \
    }

    STAGE_AB(0, 0);
    __syncthreads();

    for (int ks = 0; ks < nk; ks++) {
        const int cur = ks & 1;
        if (ks + 1 < nk) STAGE_AB(cur ^ 1, (ks + 1) << 6);  // in flight across compute
        const u16* Asb = sh[cur][0];
        const u16* Bsb = sh[cur][1];
        __builtin_amdgcn_s_setprio(1);
#pragma unroll
        for (int kk = 0; kk < 2; kk++) {
            bf16x8 af[4], bfr[4];
#pragma unroll
            for (int m = 0; m < 4; m++)
                af[m] = *(const bf16x8*)&Asb[(wr * 64 + m * 16 + c) * 64 + kk * 32 + g * 8];
#pragma unroll
            for (int n = 0; n < 4; n++)
                bfr[n] = *(const bf16x8*)&Bsb[(wc * 64 + n * 16 + c) * 64 + kk * 32 + g * 8];
#pragma unroll
            for (int m = 0; m < 4; m++)
#pragma unroll
                for (int n = 0; n < 4; n++)
                    acc[m][n] = __builtin_amdgcn_mfma_f32_16x16x32_bf16(
                        af[m], bfr[n], acc[m][n], 0, 0, 0);
        }
        __builtin_amdgcn_s_setprio(0);
        __syncthreads();   // staged next-tile landed; all waves done with cur
    }
#undef STAGE_AB

    if constexpr (MODE == MODE_QKV) {
        if (bn >= 12) {
            // ---- V section: LDS tile transpose, coalesced V^T stores ----
#pragma unroll
            for (int m = 0; m < 4; m++) {
#pragma unroll
                for (int n = 0; n < 4; n++) {
                    const int colL = wc * 64 + n * 16 + c;
                    const int rowLb = wr * 64 + m * 16 + 4 * g;
                    const float bv = bias[bn * 128 + colL];
                    const u32 x0 = packbf(acc[m][n][0] + bv, acc[m][n][1] + bv);
                    const u32 x1 = packbf(acc[m][n][2] + bv, acc[m][n][3] + bv);
                    const int elem = colL * 128 + (rowLb ^ ((colL & 15) << 3));
                    ((u32*)shp)[elem >> 1] = x0;
                    ((u32*)shp)[(elem >> 1) + 1] = x1;
                }
            }
            __syncthreads();
            const int bn_off = bn - 12;
            const int bb = bm >> 3, kvb = (bm & 7) * 128;
            const int j8 = (t & 7) * 8;
#pragma unroll
            for (int it = 0; it < 4; it++) {
                const int colL2 = it * 32 + (t >> 3);
                const int gcol = bn_off * 128 + colL2;
                const int hh = gcol >> 6, d = gcol & 63;
                const size_t obase = ((size_t)(bb * 12 + hh) << 16) + ((size_t)d << 10) + kvb;
                const int X = (colL2 & 15) << 3;
#pragma unroll
                for (int half = 0; half < 2; half++) {
                    const int rowL2 = half * 64 + j8;
                    const int elem = colL2 * 128 + (rowL2 ^ X);
                    *(u16x8*)((u16*)out2 + obase + rowL2) = *(const u16x8*)&shp[elem];
                }
            }
            return;
        }
    }

#pragma unroll
    for (int m = 0; m < 4; m++) {
        const int row = bm * 128 + wr * 64 + m * 16 + 4 * g;
#pragma unroll
        for (int n = 0; n < 4; n++) {
            const int col = bn * 128 + wc * 64 + n * 16 + c;
            const float bv = bias[col];
#pragma unroll
            for (int i = 0; i < 4; i++) {
                float v = acc[m][n][i] + bv;
                if constexpr (MODE == MODE_GELU) {
                    ((u16*)out0)[(size_t)(row + i) * N + col] = f2bf(fast_gelu(v));
                } else if constexpr (MODE == MODE_RESF32) {
                    const size_t idx = (size_t)(row + i) * N + col;
                    ((float*)out0)[idx] = v + res[idx];
                } else {
                    const int sect = (col >= 768) ? 1 : 0;
                    const int colm = col - sect * 768;
                    u16* dst = sect ? (u16*)out1 : (u16*)out0;
                    dst[(size_t)(row + i) * 768 + colm] = f2bf(v);
                }
            }
        }
    }
}

// ---------------------------------------------------------------------------
// Flash attention v3 (unchanged from round 7): swapped QK^T, in-register
// softmax, double-buffered swizzled-source K/V staging, XCD head mapping.
// ---------------------------------------------------------------------------
__global__ __launch_bounds__(256) void attn_kernel(
    const u16* __restrict__ Qg, const u16* __restrict__ Kg,
    const u16* __restrict__ Vt_g, u16* __restrict__ O)
{
    __shared__ u16 Kl[2][4096];
    __shared__ u16 Vl[2][4096];
    const int t = threadIdx.x, lane = t & 63, wave = t >> 6;
    const int g = lane >> 4, c = lane & 15;
    const int l = blockIdx.x;
    const int pos = l >> 3;
    const int bh = (l & 7) * 12 + (pos >> 3);
    const int qt = pos & 7;
    const int b = bh / 12, h = bh % 12;
    const size_t rowb = (size_t)b * 1024;
    const int q0 = qt * 128 + wave * 32;

    bf16x8 qa[2], qb[2];
    {
        const u16* qp = Qg + (rowb + q0 + c) * 768 + h * 64 + g * 8;
        u16x8 a0 = *(const u16x8*)qp;
        u16x8 a1 = *(const u16x8*)(qp + 32);
        u16x8 b0 = *(const u16x8*)(qp + 16 * 768);
        u16x8 b1 = *(const u16x8*)(qp + 16 * 768 + 32);
        bf16x8 va0, va1, vb0, vb1;
#pragma unroll
        for (int j = 0; j < 8; j++) {
            const float SC = 0.18033688011112042f;   // 0.125 * log2(e)
            va0[j] = (__bf16)(__uint_as_float(((u32)a0[j]) << 16) * SC);
            va1[j] = (__bf16)(__uint_as_float(((u32)a1[j]) << 16) * SC);
            vb0[j] = (__bf16)(__uint_as_float(((u32)b0[j]) << 16) * SC);
            vb1[j] = (__bf16)(__uint_as_float(((u32)b1[j]) << 16) * SC);
        }
        qa[0] = va0; qa[1] = va1; qb[0] = vb0; qb[1] = vb1;
    }

    int kro[4], kxo[4], vro[4];
#pragma unroll
    for (int n = 0; n < 4; n++) {
        const int pr = ((n >> 1) << 5) + ((c >> 2) << 3) + ((n & 1) << 2) + (c & 3);
        kro[n] = pr << 6;
        kxo[n] = (((pr >> 3) & 1) << 2) | (pr & 3);
        vro[n] = (n * 16 + c) << 6;
    }
    const int vxo = (((c >> 3) & 1) << 2) | (c & 3);

    const u16* ksrc = Kg + rowb * 768 + h * 64;
    const u16* vsrc = Vt_g + (size_t)bh * 65536;

    float m0 = -1e30f, l0 = 0.f, m1 = -1e30f, l1 = 0.f;
    f32x4 oa[4] = {}, ob[4] = {};
    const int srcb = (lane & 48) | ((lane >> 2) & 12);

    stage64(ksrc, 768, Kl[0], t);
    stage64(vsrc, 1024, Vl[0], t);
    __syncthreads();

    for (int kvt = 0; kvt < 16; ++kvt) {
        const u16* Kc = Kl[kvt & 1];
        const u16* Vc = Vl[kvt & 1];
        if (kvt < 15) {
            stage64(ksrc + (size_t)(kvt + 1) * 64 * 768, 768, Kl[(kvt + 1) & 1], t);
            stage64(vsrc + (kvt + 1) * 64, 1024, Vl[(kvt + 1) & 1], t);
        }

        f32x4 s0[4] = {}, s1[4] = {};
#pragma unroll
        for (int n = 0; n < 4; n++) {
#pragma unroll
            for (int kk = 0; kk < 2; kk++) {
                const bf16x8 kf = *(const bf16x8*)&Kc[kro[n] + ((((kk << 2) + g) ^ kxo[n]) << 3)];
                s0[n] = __builtin_amdgcn_mfma_f32_16x16x32_bf16(kf, qa[kk], s0[n], 0, 0, 0);
                s1[n] = __builtin_amdgcn_mfma_f32_16x16x32_bf16(kf, qb[kk], s1[n], 0, 0, 0);
            }
        }

        bf16x8 pa00, pa01;
        {
            float t0 = fmaxf(fmaxf(s0[0][0], s0[0][1]), fmaxf(s0[0][2], s0[0][3]));
            float t1 = fmaxf(fmaxf(s0[1][0], s0[1][1]), fmaxf(s0[1][2], s0[1][3]));
            float t2 = fmaxf(fmaxf(s0[2][0], s0[2][1]), fmaxf(s0[2][2], s0[2][3]));
            float t3 = fmaxf(fmaxf(s0[3][0], s0[3][1]), fmaxf(s0[3][2], s0[3][3]));
            float mx = fmaxf(fmaxf(t0, t1), fmaxf(t2, t3));
            mx = fmaxf(mx, __shfl_xor(mx, 16, 64));
            mx = fmaxf(mx, __shfl_xor(mx, 32, 64));
            if (!__all(mx <= m0 + 8.0f)) {
                const float mn = fmaxf(m0, mx);
                const float rsc = exp2f(m0 - mn);
                m0 = mn; l0 *= rsc;
                f32x4 rq;
#pragma unroll
                for (int i = 0; i < 4; i++) rq[i] = __shfl(rsc, srcb + i, 64);
#pragma unroll
                for (int n = 0; n < 4; n++) oa[n] *= rq;
            }
            float r = 0.f;
#pragma unroll
            for (int n = 0; n < 4; n++)
#pragma unroll
                for (int i = 0; i < 4; i++) {
                    s0[n][i] = exp2f(s0[n][i] - m0);
                    r += s0[n][i];
                }
            r += __shfl_xor(r, 16, 64);
            r += __shfl_xor(r, 32, 64);
            l0 += r;
#pragma unroll
            for (int i = 0; i < 4; i++) {
                pa00[i] = (__bf16)s0[0][i]; pa00[4 + i] = (__bf16)s0[1][i];
                pa01[i] = (__bf16)s0[2][i]; pa01[4 + i] = (__bf16)s0[3][i];
            }
        }
        bf16x8 pa10, pa11;
        {
            float t0 = fmaxf(fmaxf(s1[0][0], s1[0][1]), fmaxf(s1[0][2], s1[0][3]));
            float t1 = fmaxf(fmaxf(s1[1][0], s1[1][1]), fmaxf(s1[1][2], s1[1][3]));
            float t2 = fmaxf(fmaxf(s1[2][0], s1[2][1]), fmaxf(s1[2][2], s1[2][3]));
            float t3 = fmaxf(fmaxf(s1[3][0], s1[3][1]), fmaxf(s1[3][2], s1[3][3]));
            float mx = fmaxf(fmaxf(t0, t1), fmaxf(t2, t3));
            mx = fmaxf(mx, __shfl_xor(mx, 16, 64));
            mx = fmaxf(mx, __shfl_xor(mx, 32, 64));
            if (!__all(mx <= m1 + 8.0f)) {
                const float mn = fmaxf(m1, mx);
                const float rsc = exp2f(m1 - mn);
                m1 = mn; l1 *= rsc;
                f32x4 rq;
#pragma unroll
                for (int i = 0; i < 4; i++) rq[i] = __shfl(rsc, srcb + i, 64);
#pragma unroll
                for (int n = 0; n < 4; n++) ob[n] *= rq;
            }
            float r = 0.f;
#pragma unroll
            for (int n = 0; n < 4; n++)
#pragma unroll
                for (int i = 0; i < 4; i++) {
                    s1[n][i] = exp2f(s1[n][i] - m1);
                    r += s1[n][i];
                }
            r += __shfl_xor(r, 16, 64);
            r += __shfl_xor(r, 32, 64);
            l1 += r;
#pragma unroll
            for (int i = 0; i < 4; i++) {
                pa10[i] = (__bf16)s1[0][i]; pa10[4 + i] = (__bf16)s1[1][i];
                pa11[i] = (__bf16)s1[2][i]; pa11[4 + i] = (__bf16)s1[3][i];
            }
        }

#pragma unroll
        for (int n = 0; n < 4; n++) {
#pragma unroll
            for (int kk = 0; kk < 2; kk++) {
                const bf16x8 vf = *(const bf16x8*)&Vc[vro[n] + ((((kk << 2) + g) ^ vxo) << 3)];
                oa[n] = __builtin_amdgcn_mfma_f32_16x16x32_bf16(kk ? pa01 : pa00, vf, oa[n], 0, 0, 0);
                ob[n] = __builtin_amdgcn_mfma_f32_16x16x32_bf16(kk ? pa11 : pa10, vf, ob[n], 0, 0, 0);
            }
        }
        __syncthreads();
    }

#pragma unroll
    for (int i = 0; i < 4; i++) {
        const float la = __shfl(l0, srcb + i, 64);
        const float lb = __shfl(l1, srcb + i, 64);
        const float ia_ = 1.0f / fmaxf(la, 1e-30f);
        const float ib_ = 1.0f / fmaxf(lb, 1e-30f);
        const size_t ra_ = rowb + q0 + 4 * g + i;
#pragma unroll
        for (int n = 0; n < 4; n++) {
            O[ra_ * 768 + h * 64 + n * 16 + c]        = f2bf(oa[n][i] * ia_);
            O[(ra_ + 16) * 768 + h * 64 + n * 16 + c] = f2bf(ob[n][i] * ib_);
        }
    }
}

// ---------------------------------------------------------------------------
// Launch
// ---------------------------------------------------------------------------
extern "C" void kernel_launch(void* const* d_in, const int* in_sizes, int n_in,
                              void* d_out, int out_size, void* d_ws, size_t ws_size,
                              hipStream_t stream)
{
    const float* x   = (const float*)d_in[0];
    const float* wq  = (const float*)d_in[1];
    const float* bq  = (const float*)d_in[2];
    const float* wk  = (const float*)d_in[3];
    const float* bk  = (const float*)d_in[4];
    const float* wv  = (const float*)d_in[5];
    const float* bv  = (const float*)d_in[6];
    const float* wo  = (const float*)d_in[7];
    const float* bo  = (const float*)d_in[8];
    const float* w1  = (const float*)d_in[9];
    const float* b1  = (const float*)d_in[10];
    const float* w2  = (const float*)d_in[11];
    const float* b2  = (const float*)d_in[12];
    const float* g1  = (const float*)d_in[13];
    const float* be1 = (const float*)d_in[14];
    const float* g2  = (const float*)d_in[15];
    const float* be2 = (const float*)d_in[16];

    char* ws = (char*)d_ws;
    constexpr size_t O_WQKV = 0;                       // [2304][768] bf16
    constexpr size_t O_WO   = 3538944;                 // [768][768]  bf16
    constexpr size_t O_W1   = 4718592;                 // [3072][768] bf16
    constexpr size_t O_W2   = 9437184;                 // [768][3072] bf16
    constexpr size_t O_BQKV = 14155776;                // [2304] f32
    constexpr size_t O_XLN  = 14168064;                // [8192][768] bf16
    constexpr size_t O_Q    = O_XLN + 12582912;
    constexpr size_t O_K    = O_Q + 12582912;
    constexpr size_t O_VT   = O_K + 12582912;          // [96][64][1024] bf16
    constexpr size_t O_ATTN = O_VT + 12582912;
    constexpr size_t O_H    = O_ATTN + 12582912;       // [8192][768] f32
    constexpr size_t O_F    = O_XLN;                   // overlays xln..VT
    constexpr size_t O_HLN  = O_ATTN;                  // overlays attnb

    u16* wqkvT = (u16*)(ws + O_WQKV);
    u16* woT   = (u16*)(ws + O_WO);
    u16* w1T   = (u16*)(ws + O_W1);
    u16* w2T   = (u16*)(ws + O_W2);
    float* bqkv = (float*)(ws + O_BQKV);
    u16* xln   = (u16*)(ws + O_XLN);
    u16* Qb    = (u16*)(ws + O_Q);
    u16* Kb    = (u16*)(ws + O_K);
    u16* VTg   = (u16*)(ws + O_VT);
    u16* attnb = (u16*)(ws + O_ATTN);
    float* h   = (float*)(ws + O_H);
    u16* fb    = (u16*)(ws + O_F);
    u16* hln   = (u16*)(ws + O_HLN);

    dim3 blk(256);
    prep_kernel<<<6921, blk, 0, stream>>>(wq, wk, wv, wo, w1, w2, bq, bk, bv,
                                          wqkvT, woT, w1T, w2T, bqkv);
    ln_kernel<<<8192, blk, 0, stream>>>(x, xln, g1, be1);
    gemm_kernel<MODE_QKV><<<dim3(64, 18), blk, 0, stream>>>(
        xln, wqkvT, bqkv, nullptr, Qb, Kb, VTg, 8192, 2304, 768);
    attn_kernel<<<768, blk, 0, stream>>>(Qb, Kb, VTg, attnb);
    gemm_kernel<MODE_RESF32><<<dim3(64, 6), blk, 0, stream>>>(
        attnb, woT, bo, x, h, nullptr, nullptr, 8192, 768, 768);
    ln_kernel<<<8192, blk, 0, stream>>>(h, hln, g2, be2);
    gemm_kernel<MODE_GELU><<<dim3(64, 24), blk, 0, stream>>>(
        hln, w1T, b1, nullptr, fb, nullptr, nullptr, 8192, 3072, 768);
    gemm_kernel<MODE_RESF32><<<dim3(64, 6), blk, 0, stream>>>(
        fb, w2T, b2, h, (float*)d_out, nullptr, nullptr, 8192, 768, 3072);
}

// Round 9
// 269.038 us; speedup vs baseline: 1.6236x; 1.0306x over previous
//
#include <hip/hip_runtime.h>
#include <hip/hip_bf16.h>
#include <math.h>

typedef unsigned short u16;
typedef unsigned int u32;
typedef u16 u16x8 __attribute__((ext_vector_type(8)));
typedef __bf16 bf16x8 __attribute__((ext_vector_type(8)));
typedef float f32x4 __attribute__((ext_vector_type(4)));

#define MODE_GELU 1
#define MODE_RESF32 2
#define MODE_QKV 3

template <typename T, typename F>
__device__ __forceinline__ T bitcast(F f) { return __builtin_bit_cast(T, f); }

__device__ __forceinline__ u16 f2bf(float f) {
    unsigned int u = __float_as_uint(f);
    u = (u + 0x7fffu + ((u >> 16) & 1u)) >> 16;
    return (u16)u;
}

__device__ __forceinline__ u32 packbf(float lo, float hi) {
    return (u32)f2bf(lo) | ((u32)f2bf(hi) << 16);
}

// branch-free GELU: x * sigmoid(1.5957691(x + 0.044715 x^3)); |err| vs exact
// erf-GELU ~3e-3 (<< 0.1256 threshold).
__device__ __forceinline__ float fast_gelu(float x) {
    const float arg = x * (2.30220775f + 0.10294329f * x * x);
    const float e = exp2f(arg);
    return x * (1.0f - __builtin_amdgcn_rcpf(e + 1.0f));
}

__device__ __forceinline__ void gl_lds16(const u16* g, u16* l) {
    __builtin_amdgcn_global_load_lds(
        (const __attribute__((address_space(1))) unsigned int*)(const void*)g,
        (__attribute__((address_space(3))) unsigned int*)(void*)l,
        16, 0, 0);
}

// Stage a 64-row x 64-col (u16) tile into LDS, XOR-swizzling the SOURCE so a
// later read of (row, slot^f(row)) returns logical (row, slot).
__device__ __forceinline__ void stage64(const u16* __restrict__ src, int stride,
                                        u16* __restrict__ lds, int t)
{
    const int wave = t >> 6, lane = t & 63;
#pragma unroll
    for (int i = 0; i < 2; i++) {
        const int row = i * 32 + wave * 8 + (lane >> 3);
        const int s = lane & 7;
        const int f = (((row >> 3) & 1) << 2) | (row & 3);
        gl_lds16(src + (size_t)row * stride + (size_t)((s ^ f) << 3),
                 lds + i * 2048 + wave * 512);
    }
}

// ---------------------------------------------------------------------------
// prep: 6 weight transposes + bias concat + LN1 (all pre-QKV work, one launch)
// blocks: [0,6912) transpose | [6912,6921) bias | [6921, 6921+8192) LN1 rows
// ---------------------------------------------------------------------------
__global__ __launch_bounds__(256) void prep_kernel(
    const float* __restrict__ wq, const float* __restrict__ wk,
    const float* __restrict__ wv, const float* __restrict__ wo,
    const float* __restrict__ w1, const float* __restrict__ w2,
    const float* __restrict__ bq, const float* __restrict__ bk,
    const float* __restrict__ bv,
    u16* __restrict__ wqkvT, u16* __restrict__ woT,
    u16* __restrict__ w1T, u16* __restrict__ w2T, float* __restrict__ bqkv,
    const float* __restrict__ X, u16* __restrict__ Y,
    const float* __restrict__ gp, const float* __restrict__ bp)
{
    const int blk = blockIdx.x;
    if (blk >= 6921) {
        // ---- LN1 row ----
        __shared__ float sbuf[8];
        const int row = blk - 6921, t = threadIdx.x;
        const float* xr = X + (size_t)row * 768;
        float v0 = xr[t], v1 = xr[t + 256], v2 = xr[t + 512];
        float s = v0 + v1 + v2;
        float q = v0 * v0 + v1 * v1 + v2 * v2;
#pragma unroll
        for (int m = 1; m < 64; m <<= 1) {
            s += __shfl_xor(s, m, 64);
            q += __shfl_xor(q, m, 64);
        }
        const int wave = t >> 6, lane = t & 63;
        if (lane == 0) { sbuf[wave] = s; sbuf[4 + wave] = q; }
        __syncthreads();
        s = sbuf[0] + sbuf[1] + sbuf[2] + sbuf[3];
        q = sbuf[4] + sbuf[5] + sbuf[6] + sbuf[7];
        const float mean = s * (1.0f / 768.0f);
        float ssd = fmaxf(q - 768.0f * mean * mean, 0.0f);
        const float stdv = sqrtf(ssd * (1.0f / 767.0f));
        const float scale = gp[0] / (stdv + 1e-5f);
        const float beta = bp[0];
        u16* yr = Y + (size_t)row * 768;
        yr[t]       = f2bf((v0 - mean) * scale + beta);
        yr[t + 256] = f2bf((v1 - mean) * scale + beta);
        yr[t + 512] = f2bf((v2 - mean) * scale + beta);
        return;
    }
    if (blk >= 6912) {
        const int t = (blk - 6912) * 256 + threadIdx.x;
        if (t < 2304)
            bqkv[t] = t < 768 ? bq[t] : (t < 1536 ? bk[t - 768] : bv[t - 1536]);
        return;
    }
    const float* W; u16* WT; int Krows, Ncols, lt;
    if (blk < 576)       { W = wq; WT = wqkvT;                       Krows = 768;  Ncols = 768;  lt = blk; }
    else if (blk < 1152) { W = wk; WT = wqkvT + (size_t)768 * 768;   Krows = 768;  Ncols = 768;  lt = blk - 576; }
    else if (blk < 1728) { W = wv; WT = wqkvT + (size_t)1536 * 768;  Krows = 768;  Ncols = 768;  lt = blk - 1152; }
    else if (blk < 2304) { W = wo; WT = woT;                         Krows = 768;  Ncols = 768;  lt = blk - 1728; }
    else if (blk < 4608) { W = w1; WT = w1T;                         Krows = 768;  Ncols = 3072; lt = blk - 2304; }
    else                 { W = w2; WT = w2T;                         Krows = 3072; Ncols = 768;  lt = blk - 4608; }
    const int ktiles = Krows >> 5;
    const int k0 = (lt % ktiles) * 32, n0 = (lt / ktiles) * 32;

    __shared__ float tile[32][33];
    const int tx = threadIdx.x & 31, ty = threadIdx.x >> 5;
#pragma unroll
    for (int j = 0; j < 32; j += 8)
        tile[ty + j][tx] = W[(size_t)(k0 + ty + j) * Ncols + n0 + tx];
    __syncthreads();
#pragma unroll
    for (int j = 0; j < 32; j += 8)
        WT[(size_t)(n0 + ty + j) * Krows + k0 + tx] = f2bf(tile[tx][ty + j]);
}

// ---------------------------------------------------------------------------
// LayerNorm (standalone, for LN2)
// ---------------------------------------------------------------------------
__global__ __launch_bounds__(256) void ln_kernel(
    const float* __restrict__ X, u16* __restrict__ Y,
    const float* __restrict__ gp, const float* __restrict__ bp)
{
    __shared__ float sbuf[8];
    const int row = blockIdx.x, t = threadIdx.x;
    const float* xr = X + (size_t)row * 768;
    float v0 = xr[t], v1 = xr[t + 256], v2 = xr[t + 512];
    float s = v0 + v1 + v2;
    float q = v0 * v0 + v1 * v1 + v2 * v2;
#pragma unroll
    for (int m = 1; m < 64; m <<= 1) {
        s += __shfl_xor(s, m, 64);
        q += __shfl_xor(q, m, 64);
    }
    const int wave = t >> 6, lane = t & 63;
    if (lane == 0) { sbuf[wave] = s; sbuf[4 + wave] = q; }
    __syncthreads();
    s = sbuf[0] + sbuf[1] + sbuf[2] + sbuf[3];
    q = sbuf[4] + sbuf[5] + sbuf[6] + sbuf[7];
    const float mean = s * (1.0f / 768.0f);
    float ssd = fmaxf(q - 768.0f * mean * mean, 0.0f);
    const float stdv = sqrtf(ssd * (1.0f / 767.0f));
    const float scale = gp[0] / (stdv + 1e-5f);
    const float beta = bp[0];
    u16* yr = Y + (size_t)row * 768;
    yr[t]       = f2bf((v0 - mean) * scale + beta);
    yr[t + 256] = f2bf((v1 - mean) * scale + beta);
    yr[t + 512] = f2bf((v2 - mean) * scale + beta);
}

// ---------------------------------------------------------------------------
// GEMM: 2-phase double-buffered (unchanged from round 8).
// ---------------------------------------------------------------------------
template <int MODE>
__global__ __launch_bounds__(256) void gemm_kernel(
    const u16* __restrict__ A, const u16* __restrict__ BT,
    const float* __restrict__ bias, const float* __restrict__ res,
    void* __restrict__ out0, void* __restrict__ out1, void* __restrict__ out2,
    int M, int N, int K)
{
    __shared__ u16 sh[2][2][128 * 64];
    u16* shp = &sh[0][0][0];
    const int t = threadIdx.x;
    const int lane = t & 63, wave = t >> 6;
    const int wr = wave >> 1, wc = wave & 1;
    const int g = lane >> 4, c = lane & 15;
    const int bm = blockIdx.x, bn = blockIdx.y;

    const int srow = wave * 32 + (lane >> 3);
    const int scol = (lane & 7) * 8;
    const u16* Ag = A + (size_t)(bm * 128 + srow) * K + scol;
    const u16* Bg = BT + (size_t)(bn * 128 + srow) * K + scol;

    f32x4 acc[4][4] = {};
    const int nk = K >> 6;

#define STAGE_AB(buf, k0)                                                     \
    {                                                                         \
        _Pragma("unroll")                                                     \
        for (int it = 0; it < 4; it++) {                                      \
            gl_lds16(Ag + (size_t)(it * 8) * K + (k0), &sh[buf][0][wave * 2048 + it * 512]); \
            gl_lds16(Bg + (size_t)(it * 8) * K + (k0), &sh[buf][1][wave * 2048 + it * 512]); \
        }                                                                     \
    }

    STAGE_AB(0, 0);
    __syncthreads();

    for (int ks = 0; ks < nk; ks++) {
        const int cur = ks & 1;
        if (ks + 1 < nk) STAGE_AB(cur ^ 1, (ks + 1) << 6);
        const u16* Asb = sh[cur][0];
        const u16* Bsb = sh[cur][1];
        __builtin_amdgcn_s_setprio(1);
#pragma unroll
        for (int kk = 0; kk < 2; kk++) {
            bf16x8 af[4], bfr[4];
#pragma unroll
            for (int m = 0; m < 4; m++)
                af[m] = *(const bf16x8*)&Asb[(wr * 64 + m * 16 + c) * 64 + kk * 32 + g * 8];
#pragma unroll
            for (int n = 0; n < 4; n++)
                bfr[n] = *(const bf16x8*)&Bsb[(wc * 64 + n * 16 + c) * 64 + kk * 32 + g * 8];
#pragma unroll
            for (int m = 0; m < 4; m++)
#pragma unroll
                for (int n = 0; n < 4; n++)
                    acc[m][n] = __builtin_amdgcn_mfma_f32_16x16x32_bf16(
                        af[m], bfr[n], acc[m][n], 0, 0, 0);
        }
        __builtin_amdgcn_s_setprio(0);
        __syncthreads();
    }
#undef STAGE_AB

    if constexpr (MODE == MODE_QKV) {
        if (bn >= 12) {
#pragma unroll
            for (int m = 0; m < 4; m++) {
#pragma unroll
                for (int n = 0; n < 4; n++) {
                    const int colL = wc * 64 + n * 16 + c;
                    const int rowLb = wr * 64 + m * 16 + 4 * g;
                    const float bv = bias[bn * 128 + colL];
                    const u32 x0 = packbf(acc[m][n][0] + bv, acc[m][n][1] + bv);
                    const u32 x1 = packbf(acc[m][n][2] + bv, acc[m][n][3] + bv);
                    const int elem = colL * 128 + (rowLb ^ ((colL & 15) << 3));
                    ((u32*)shp)[elem >> 1] = x0;
                    ((u32*)shp)[(elem >> 1) + 1] = x1;
                }
            }
            __syncthreads();
            const int bn_off = bn - 12;
            const int bb = bm >> 3, kvb = (bm & 7) * 128;
            const int j8 = (t & 7) * 8;
#pragma unroll
            for (int it = 0; it < 4; it++) {
                const int colL2 = it * 32 + (t >> 3);
                const int gcol = bn_off * 128 + colL2;
                const int hh = gcol >> 6, d = gcol & 63;
                const size_t obase = ((size_t)(bb * 12 + hh) << 16) + ((size_t)d << 10) + kvb;
                const int X = (colL2 & 15) << 3;
#pragma unroll
                for (int half = 0; half < 2; half++) {
                    const int rowL2 = half * 64 + j8;
                    const int elem = colL2 * 128 + (rowL2 ^ X);
                    *(u16x8*)((u16*)out2 + obase + rowL2) = *(const u16x8*)&shp[elem];
                }
            }
            return;
        }
    }

#pragma unroll
    for (int m = 0; m < 4; m++) {
        const int row = bm * 128 + wr * 64 + m * 16 + 4 * g;
#pragma unroll
        for (int n = 0; n < 4; n++) {
            const int col = bn * 128 + wc * 64 + n * 16 + c;
            const float bv = bias[col];
#pragma unroll
            for (int i = 0; i < 4; i++) {
                float v = acc[m][n][i] + bv;
                if constexpr (MODE == MODE_GELU) {
                    ((u16*)out0)[(size_t)(row + i) * N + col] = f2bf(fast_gelu(v));
                } else if constexpr (MODE == MODE_RESF32) {
                    const size_t idx = (size_t)(row + i) * N + col;
                    ((float*)out0)[idx] = v + res[idx];
                } else {
                    const int sect = (col >= 768) ? 1 : 0;
                    const int colm = col - sect * 768;
                    u16* dst = sect ? (u16*)out1 : (u16*)out0;
                    dst[(size_t)(row + i) * 768 + colm] = f2bf(v);
                }
            }
        }
    }
}

// ---------------------------------------------------------------------------
// Flash attention v4: 16 q-rows/wave (2x blocks = 2x TLP), swapped QK^T,
// in-register softmax, dbuf swizzled-source K/V staging, XCD head mapping,
// setprio around MFMA clusters.
// grid 1536: l&7 = batch(=XCD slot), (l>>3)>>4 = head, (l>>3)&15 = q-tile.
// ---------------------------------------------------------------------------
__global__ __launch_bounds__(256) void attn_kernel(
    const u16* __restrict__ Qg, const u16* __restrict__ Kg,
    const u16* __restrict__ Vt_g, u16* __restrict__ O)
{
    __shared__ u16 Kl[2][4096];
    __shared__ u16 Vl[2][4096];
    const int t = threadIdx.x, lane = t & 63, wave = t >> 6;
    const int g = lane >> 4, c = lane & 15;
    const int l = blockIdx.x;
    const int pos = l >> 3;
    const int b = l & 7, h = pos >> 4;
    const int qt = pos & 15;
    const int bh = b * 12 + h;
    const size_t rowb = (size_t)b * 1024;
    const int q0 = qt * 64 + wave * 16;

    bf16x8 qa[2];
    {
        const u16* qp = Qg + (rowb + q0 + c) * 768 + h * 64 + g * 8;
        u16x8 a0 = *(const u16x8*)qp;
        u16x8 a1 = *(const u16x8*)(qp + 32);
        bf16x8 va0, va1;
#pragma unroll
        for (int j = 0; j < 8; j++) {
            const float SC = 0.18033688011112042f;   // 0.125 * log2(e)
            va0[j] = (__bf16)(__uint_as_float(((u32)a0[j]) << 16) * SC);
            va1[j] = (__bf16)(__uint_as_float(((u32)a1[j]) << 16) * SC);
        }
        qa[0] = va0; qa[1] = va1;
    }

    int kro[4], kxo[4], vro[4];
#pragma unroll
    for (int n = 0; n < 4; n++) {
        const int pr = ((n >> 1) << 5) + ((c >> 2) << 3) + ((n & 1) << 2) + (c & 3);
        kro[n] = pr << 6;
        kxo[n] = (((pr >> 3) & 1) << 2) | (pr & 3);
        vro[n] = (n * 16 + c) << 6;
    }
    const int vxo = (((c >> 3) & 1) << 2) | (c & 3);

    const u16* ksrc = Kg + rowb * 768 + h * 64;
    const u16* vsrc = Vt_g + (size_t)bh * 65536;

    float m0 = -1e30f, l0 = 0.f;
    f32x4 oa[4] = {};
    const int srcb = (lane & 48) | ((lane >> 2) & 12);

    stage64(ksrc, 768, Kl[0], t);
    stage64(vsrc, 1024, Vl[0], t);
    __syncthreads();

    for (int kvt = 0; kvt < 16; ++kvt) {
        const u16* Kc = Kl[kvt & 1];
        const u16* Vc = Vl[kvt & 1];
        if (kvt < 15) {
            stage64(ksrc + (size_t)(kvt + 1) * 64 * 768, 768, Kl[(kvt + 1) & 1], t);
            stage64(vsrc + (kvt + 1) * 64, 1024, Vl[(kvt + 1) & 1], t);
        }

        f32x4 s0[4] = {};
        __builtin_amdgcn_s_setprio(1);
#pragma unroll
        for (int n = 0; n < 4; n++) {
#pragma unroll
            for (int kk = 0; kk < 2; kk++) {
                const bf16x8 kf = *(const bf16x8*)&Kc[kro[n] + ((((kk << 2) + g) ^ kxo[n]) << 3)];
                s0[n] = __builtin_amdgcn_mfma_f32_16x16x32_bf16(kf, qa[kk], s0[n], 0, 0, 0);
            }
        }
        __builtin_amdgcn_s_setprio(0);

        bf16x8 pa00, pa01;
        {
            float t0 = fmaxf(fmaxf(s0[0][0], s0[0][1]), fmaxf(s0[0][2], s0[0][3]));
            float t1 = fmaxf(fmaxf(s0[1][0], s0[1][1]), fmaxf(s0[1][2], s0[1][3]));
            float t2 = fmaxf(fmaxf(s0[2][0], s0[2][1]), fmaxf(s0[2][2], s0[2][3]));
            float t3 = fmaxf(fmaxf(s0[3][0], s0[3][1]), fmaxf(s0[3][2], s0[3][3]));
            float mx = fmaxf(fmaxf(t0, t1), fmaxf(t2, t3));
            mx = fmaxf(mx, __shfl_xor(mx, 16, 64));
            mx = fmaxf(mx, __shfl_xor(mx, 32, 64));
            if (!__all(mx <= m0 + 8.0f)) {
                const float mn = fmaxf(m0, mx);
                const float rsc = exp2f(m0 - mn);
                m0 = mn; l0 *= rsc;
                f32x4 rq;
#pragma unroll
                for (int i = 0; i < 4; i++) rq[i] = __shfl(rsc, srcb + i, 64);
#pragma unroll
                for (int n = 0; n < 4; n++) oa[n] *= rq;
            }
            float r = 0.f;
#pragma unroll
            for (int n = 0; n < 4; n++)
#pragma unroll
                for (int i = 0; i < 4; i++) {
                    s0[n][i] = exp2f(s0[n][i] - m0);
                    r += s0[n][i];
                }
            r += __shfl_xor(r, 16, 64);
            r += __shfl_xor(r, 32, 64);
            l0 += r;
#pragma unroll
            for (int i = 0; i < 4; i++) {
                pa00[i] = (__bf16)s0[0][i]; pa00[4 + i] = (__bf16)s0[1][i];
                pa01[i] = (__bf16)s0[2][i]; pa01[4 + i] = (__bf16)s0[3][i];
            }
        }

        __builtin_amdgcn_s_setprio(1);
#pragma unroll
        for (int n = 0; n < 4; n++) {
#pragma unroll
            for (int kk = 0; kk < 2; kk++) {
                const bf16x8 vf = *(const bf16x8*)&Vc[vro[n] + ((((kk << 2) + g) ^ vxo) << 3)];
                oa[n] = __builtin_amdgcn_mfma_f32_16x16x32_bf16(kk ? pa01 : pa00, vf, oa[n], 0, 0, 0);
            }
        }
        __builtin_amdgcn_s_setprio(0);
        __syncthreads();
    }

#pragma unroll
    for (int i = 0; i < 4; i++) {
        const float la = __shfl(l0, srcb + i, 64);
        const float ia_ = 1.0f / fmaxf(la, 1e-30f);
        const size_t ra_ = rowb + q0 + 4 * g + i;
#pragma unroll
        for (int n = 0; n < 4; n++)
            O[ra_ * 768 + h * 64 + n * 16 + c] = f2bf(oa[n][i] * ia_);
    }
}

// ---------------------------------------------------------------------------
// Launch
// ---------------------------------------------------------------------------
extern "C" void kernel_launch(void* const* d_in, const int* in_sizes, int n_in,
                              void* d_out, int out_size, void* d_ws, size_t ws_size,
                              hipStream_t stream)
{
    const float* x   = (const float*)d_in[0];
    const float* wq  = (const float*)d_in[1];
    const float* bq  = (const float*)d_in[2];
    const float* wk  = (const float*)d_in[3];
    const float* bk  = (const float*)d_in[4];
    const float* wv  = (const float*)d_in[5];
    const float* bv  = (const float*)d_in[6];
    const float* wo  = (const float*)d_in[7];
    const float* bo  = (const float*)d_in[8];
    const float* w1  = (const float*)d_in[9];
    const float* b1  = (const float*)d_in[10];
    const float* w2  = (const float*)d_in[11];
    const float* b2  = (const float*)d_in[12];
    const float* g1  = (const float*)d_in[13];
    const float* be1 = (const float*)d_in[14];
    const float* g2  = (const float*)d_in[15];
    const float* be2 = (const float*)d_in[16];

    char* ws = (char*)d_ws;
    constexpr size_t O_WQKV = 0;                       // [2304][768] bf16
    constexpr size_t O_WO   = 3538944;                 // [768][768]  bf16
    constexpr size_t O_W1   = 4718592;                 // [3072][768] bf16
    constexpr size_t O_W2   = 9437184;                 // [768][3072] bf16
    constexpr size_t O_BQKV = 14155776;                // [2304] f32
    constexpr size_t O_XLN  = 14168064;                // [8192][768] bf16
    constexpr size_t O_Q    = O_XLN + 12582912;
    constexpr size_t O_K    = O_Q + 12582912;
    constexpr size_t O_VT   = O_K + 12582912;          // [96][64][1024] bf16
    constexpr size_t O_ATTN = O_VT + 12582912;
    constexpr size_t O_H    = O_ATTN + 12582912;       // [8192][768] f32
    constexpr size_t O_F    = O_XLN;                   // overlays xln..VT
    constexpr size_t O_HLN  = O_ATTN;                  // overlays attnb

    u16* wqkvT = (u16*)(ws + O_WQKV);
    u16* woT   = (u16*)(ws + O_WO);
    u16* w1T   = (u16*)(ws + O_W1);
    u16* w2T   = (u16*)(ws + O_W2);
    float* bqkv = (float*)(ws + O_BQKV);
    u16* xln   = (u16*)(ws + O_XLN);
    u16* Qb    = (u16*)(ws + O_Q);
    u16* Kb    = (u16*)(ws + O_K);
    u16* VTg   = (u16*)(ws + O_VT);
    u16* attnb = (u16*)(ws + O_ATTN);
    float* h   = (float*)(ws + O_H);
    u16* fb    = (u16*)(ws + O_F);
    u16* hln   = (u16*)(ws + O_HLN);

    dim3 blk(256);
    prep_kernel<<<6921 + 8192, blk, 0, stream>>>(wq, wk, wv, wo, w1, w2, bq, bk, bv,
                                                 wqkvT, woT, w1T, w2T, bqkv,
                                                 x, xln, g1, be1);
    gemm_kernel<MODE_QKV><<<dim3(64, 18), blk, 0, stream>>>(
        xln, wqkvT, bqkv, nullptr, Qb, Kb, VTg, 8192, 2304, 768);
    attn_kernel<<<1536, blk, 0, stream>>>(Qb, Kb, VTg, attnb);
    gemm_kernel<MODE_RESF32><<<dim3(64, 6), blk, 0, stream>>>(
        attnb, woT, bo, x, h, nullptr, nullptr, 8192, 768, 768);
    ln_kernel<<<8192, blk, 0, stream>>>(h, hln, g2, be2);
    gemm_kernel<MODE_GELU><<<dim3(64, 24), blk, 0, stream>>>(
        hln, w1T, b1, nullptr, fb, nullptr, nullptr, 8192, 3072, 768);
    gemm_kernel<MODE_RESF32><<<dim3(64, 6), blk, 0, stream>>>(
        fb, w2T, b2, h, (float*)d_out, nullptr, nullptr, 8192, 768, 3072);
}

// Round 10
// 242.547 us; speedup vs baseline: 1.8010x; 1.1092x over previous
//
#include <hip/hip_runtime.h>
#include <hip/hip_bf16.h>
#include <math.h>

typedef unsigned short u16;
typedef unsigned int u32;
typedef u16 u16x8 __attribute__((ext_vector_type(8)));
typedef __bf16 bf16x8 __attribute__((ext_vector_type(8)));
typedef float f32x4 __attribute__((ext_vector_type(4)));

#define MODE_GELU 1
#define MODE_RESF32 2
#define MODE_QKV 3

template <typename T, typename F>
__device__ __forceinline__ T bitcast(F f) { return __builtin_bit_cast(T, f); }

__device__ __forceinline__ u16 f2bf(float f) {
    unsigned int u = __float_as_uint(f);
    u = (u + 0x7fffu + ((u >> 16) & 1u)) >> 16;
    return (u16)u;
}

__device__ __forceinline__ u32 packbf(float lo, float hi) {
    return (u32)f2bf(lo) | ((u32)f2bf(hi) << 16);
}

// branch-free GELU: x * sigmoid(1.5957691(x + 0.044715 x^3)); |err| vs exact
// erf-GELU ~3e-3 (<< 0.1256 threshold).
__device__ __forceinline__ float fast_gelu(float x) {
    const float arg = x * (2.30220775f + 0.10294329f * x * x);
    const float e = exp2f(arg);
    return x * (1.0f - __builtin_amdgcn_rcpf(e + 1.0f));
}

__device__ __forceinline__ void gl_lds16(const u16* g, u16* l) {
    __builtin_amdgcn_global_load_lds(
        (const __attribute__((address_space(1))) unsigned int*)(const void*)g,
        (__attribute__((address_space(3))) unsigned int*)(void*)l,
        16, 0, 0);
}

// Stage a 64-row x 64-col (u16) tile into LDS, XOR-swizzling the SOURCE so a
// later read of (row, slot^f(row)) returns logical (row, slot).
__device__ __forceinline__ void stage64(const u16* __restrict__ src, int stride,
                                        u16* __restrict__ lds, int t)
{
    const int wave = t >> 6, lane = t & 63;
#pragma unroll
    for (int i = 0; i < 2; i++) {
        const int row = i * 32 + wave * 8 + (lane >> 3);
        const int s = lane & 7;
        const int f = (((row >> 3) & 1) << 2) | (row & 3);
        gl_lds16(src + (size_t)row * stride + (size_t)((s ^ f) << 3),
                 lds + i * 2048 + wave * 512);
    }
}

// ---------------------------------------------------------------------------
// prep: 6 weight transposes + bias concat + LN1 (all pre-QKV work, one launch)
// ---------------------------------------------------------------------------
__global__ __launch_bounds__(256) void prep_kernel(
    const float* __restrict__ wq, const float* __restrict__ wk,
    const float* __restrict__ wv, const float* __restrict__ wo,
    const float* __restrict__ w1, const float* __restrict__ w2,
    const float* __restrict__ bq, const float* __restrict__ bk,
    const float* __restrict__ bv,
    u16* __restrict__ wqkvT, u16* __restrict__ woT,
    u16* __restrict__ w1T, u16* __restrict__ w2T, float* __restrict__ bqkv,
    const float* __restrict__ X, u16* __restrict__ Y,
    const float* __restrict__ gp, const float* __restrict__ bp)
{
    const int blk = blockIdx.x;
    if (blk >= 6921) {
        // ---- LN1 row ----
        __shared__ float sbuf[8];
        const int row = blk - 6921, t = threadIdx.x;
        const float* xr = X + (size_t)row * 768;
        float v0 = xr[t], v1 = xr[t + 256], v2 = xr[t + 512];
        float s = v0 + v1 + v2;
        float q = v0 * v0 + v1 * v1 + v2 * v2;
#pragma unroll
        for (int m = 1; m < 64; m <<= 1) {
            s += __shfl_xor(s, m, 64);
            q += __shfl_xor(q, m, 64);
        }
        const int wave = t >> 6, lane = t & 63;
        if (lane == 0) { sbuf[wave] = s; sbuf[4 + wave] = q; }
        __syncthreads();
        s = sbuf[0] + sbuf[1] + sbuf[2] + sbuf[3];
        q = sbuf[4] + sbuf[5] + sbuf[6] + sbuf[7];
        const float mean = s * (1.0f / 768.0f);
        float ssd = fmaxf(q - 768.0f * mean * mean, 0.0f);
        const float stdv = sqrtf(ssd * (1.0f / 767.0f));
        const float scale = gp[0] / (stdv + 1e-5f);
        const float beta = bp[0];
        u16* yr = Y + (size_t)row * 768;
        yr[t]       = f2bf((v0 - mean) * scale + beta);
        yr[t + 256] = f2bf((v1 - mean) * scale + beta);
        yr[t + 512] = f2bf((v2 - mean) * scale + beta);
        return;
    }
    if (blk >= 6912) {
        const int t = (blk - 6912) * 256 + threadIdx.x;
        if (t < 2304)
            bqkv[t] = t < 768 ? bq[t] : (t < 1536 ? bk[t - 768] : bv[t - 1536]);
        return;
    }
    const float* W; u16* WT; int Krows, Ncols, lt;
    if (blk < 576)       { W = wq; WT = wqkvT;                       Krows = 768;  Ncols = 768;  lt = blk; }
    else if (blk < 1152) { W = wk; WT = wqkvT + (size_t)768 * 768;   Krows = 768;  Ncols = 768;  lt = blk - 576; }
    else if (blk < 1728) { W = wv; WT = wqkvT + (size_t)1536 * 768;  Krows = 768;  Ncols = 768;  lt = blk - 1152; }
    else if (blk < 2304) { W = wo; WT = woT;                         Krows = 768;  Ncols = 768;  lt = blk - 1728; }
    else if (blk < 4608) { W = w1; WT = w1T;                         Krows = 768;  Ncols = 3072; lt = blk - 2304; }
    else                 { W = w2; WT = w2T;                         Krows = 3072; Ncols = 768;  lt = blk - 4608; }
    const int ktiles = Krows >> 5;
    const int k0 = (lt % ktiles) * 32, n0 = (lt / ktiles) * 32;

    __shared__ float tile[32][33];
    const int tx = threadIdx.x & 31, ty = threadIdx.x >> 5;
#pragma unroll
    for (int j = 0; j < 32; j += 8)
        tile[ty + j][tx] = W[(size_t)(k0 + ty + j) * Ncols + n0 + tx];
    __syncthreads();
#pragma unroll
    for (int j = 0; j < 32; j += 8)
        WT[(size_t)(n0 + ty + j) * Krows + k0 + tx] = f2bf(tile[tx][ty + j]);
}

// ---------------------------------------------------------------------------
// LayerNorm (standalone, for LN2)
// ---------------------------------------------------------------------------
__global__ __launch_bounds__(256) void ln_kernel(
    const float* __restrict__ X, u16* __restrict__ Y,
    const float* __restrict__ gp, const float* __restrict__ bp)
{
    __shared__ float sbuf[8];
    const int row = blockIdx.x, t = threadIdx.x;
    const float* xr = X + (size_t)row * 768;
    float v0 = xr[t], v1 = xr[t + 256], v2 = xr[t + 512];
    float s = v0 + v1 + v2;
    float q = v0 * v0 + v1 * v1 + v2 * v2;
#pragma unroll
    for (int m = 1; m < 64; m <<= 1) {
        s += __shfl_xor(s, m, 64);
        q += __shfl_xor(q, m, 64);
    }
    const int wave = t >> 6, lane = t & 63;
    if (lane == 0) { sbuf[wave] = s; sbuf[4 + wave] = q; }
    __syncthreads();
    s = sbuf[0] + sbuf[1] + sbuf[2] + sbuf[3];
    q = sbuf[4] + sbuf[5] + sbuf[6] + sbuf[7];
    const float mean = s * (1.0f / 768.0f);
    float ssd = fmaxf(q - 768.0f * mean * mean, 0.0f);
    const float stdv = sqrtf(ssd * (1.0f / 767.0f));
    const float scale = gp[0] / (stdv + 1e-5f);
    const float beta = bp[0];
    u16* yr = Y + (size_t)row * 768;
    yr[t]       = f2bf((v0 - mean) * scale + beta);
    yr[t + 256] = f2bf((v1 - mean) * scale + beta);
    yr[t + 512] = f2bf((v2 - mean) * scale + beta);
}

// ---------------------------------------------------------------------------
// GEMM v3: 2-phase dbuf + BOTH-SIDES LDS swizzle (rule 21 / T2).
// Stage: linear LDS dest, source col XOR'd by f(row)=(((r>>3)&1)<<2)|(r&3).
// Read: slot^f(row); f collapses to per-lane const fc (row bases % 16 == 0).
// Kills the 16-way quarter-wave bank conflict of row-stride-128B tiles.
// ---------------------------------------------------------------------------
template <int MODE>
__global__ __launch_bounds__(256) void gemm_kernel(
    const u16* __restrict__ A, const u16* __restrict__ BT,
    const float* __restrict__ bias, const float* __restrict__ res,
    void* __restrict__ out0, void* __restrict__ out1, void* __restrict__ out2,
    int M, int N, int K)
{
    __shared__ u16 sh[2][2][128 * 64];
    u16* shp = &sh[0][0][0];
    const int t = threadIdx.x;
    const int lane = t & 63, wave = t >> 6;
    const int wr = wave >> 1, wc = wave & 1;
    const int g = lane >> 4, c = lane & 15;
    const int bm = blockIdx.x, bn = blockIdx.y;

    const int srow = wave * 32 + (lane >> 3);   // + it*8 at use
    const u16* Ag = A + (size_t)(bm * 128 + srow) * K;
    const u16* Bg = BT + (size_t)(bn * 128 + srow) * K;

    // read-side swizzle constant: f(row)=((c>>3)<<2)|(c&3) since row%16==c
    const int fc = (((c >> 3) & 1) << 2) | (c & 3);
    const int xs0 = (g ^ fc) << 3;              // slot kk=0 byte/2 offset
    const int xs1 = ((4 + g) ^ fc) << 3;        // slot kk=1

    f32x4 acc[4][4] = {};
    const int nk = K >> 6;

    // stage-side: it-th issue covers rows wave*32+it*8+(lane>>3);
    // f(row) = ((it&1)<<2) | ((lane>>3)&3)
    const int sl = lane & 7;
    int sco[4];
#pragma unroll
    for (int it = 0; it < 4; it++)
        sco[it] = ((sl ^ (((it & 1) << 2) | ((lane >> 3) & 3))) << 3);

#define STAGE_AB(buf, k0)                                                     \
    {                                                                         \
        _Pragma("unroll")                                                     \
        for (int it = 0; it < 4; it++) {                                      \
            gl_lds16(Ag + (size_t)(it * 8) * K + (k0) + sco[it], &sh[buf][0][wave * 2048 + it * 512]); \
            gl_lds16(Bg + (size_t)(it * 8) * K + (k0) + sco[it], &sh[buf][1][wave * 2048 + it * 512]); \
        }                                                                     \
    }

    STAGE_AB(0, 0);
    __syncthreads();

    for (int ks = 0; ks < nk; ks++) {
        const int cur = ks & 1;
        if (ks + 1 < nk) STAGE_AB(cur ^ 1, (ks + 1) << 6);
        const u16* Asb = sh[cur][0];
        const u16* Bsb = sh[cur][1];
        __builtin_amdgcn_s_setprio(1);
#pragma unroll
        for (int kk = 0; kk < 2; kk++) {
            const int xo = kk ? xs1 : xs0;
            bf16x8 af[4], bfr[4];
#pragma unroll
            for (int m = 0; m < 4; m++)
                af[m] = *(const bf16x8*)&Asb[(wr * 64 + m * 16 + c) * 64 + xo];
#pragma unroll
            for (int n = 0; n < 4; n++)
                bfr[n] = *(const bf16x8*)&Bsb[(wc * 64 + n * 16 + c) * 64 + xo];
#pragma unroll
            for (int m = 0; m < 4; m++)
#pragma unroll
                for (int n = 0; n < 4; n++)
                    acc[m][n] = __builtin_amdgcn_mfma_f32_16x16x32_bf16(
                        af[m], bfr[n], acc[m][n], 0, 0, 0);
        }
        __builtin_amdgcn_s_setprio(0);
        __syncthreads();
    }
#undef STAGE_AB

    if constexpr (MODE == MODE_QKV) {
        if (bn >= 12) {
            // ---- V section: LDS tile transpose, coalesced V^T stores ----
#pragma unroll
            for (int m = 0; m < 4; m++) {
#pragma unroll
                for (int n = 0; n < 4; n++) {
                    const int colL = wc * 64 + n * 16 + c;
                    const int rowLb = wr * 64 + m * 16 + 4 * g;
                    const float bv = bias[bn * 128 + colL];
                    const u32 x0 = packbf(acc[m][n][0] + bv, acc[m][n][1] + bv);
                    const u32 x1 = packbf(acc[m][n][2] + bv, acc[m][n][3] + bv);
                    const int elem = colL * 128 + (rowLb ^ ((colL & 15) << 3));
                    ((u32*)shp)[elem >> 1] = x0;
                    ((u32*)shp)[(elem >> 1) + 1] = x1;
                }
            }
            __syncthreads();
            const int bn_off = bn - 12;
            const int bb = bm >> 3, kvb = (bm & 7) * 128;
            const int j8 = (t & 7) * 8;
#pragma unroll
            for (int it = 0; it < 4; it++) {
                const int colL2 = it * 32 + (t >> 3);
                const int gcol = bn_off * 128 + colL2;
                const int hh = gcol >> 6, d = gcol & 63;
                const size_t obase = ((size_t)(bb * 12 + hh) << 16) + ((size_t)d << 10) + kvb;
                const int X = (colL2 & 15) << 3;
#pragma unroll
                for (int half = 0; half < 2; half++) {
                    const int rowL2 = half * 64 + j8;
                    const int elem = colL2 * 128 + (rowL2 ^ X);
                    *(u16x8*)((u16*)out2 + obase + rowL2) = *(const u16x8*)&shp[elem];
                }
            }
            return;
        }
    }

#pragma unroll
    for (int m = 0; m < 4; m++) {
        const int row = bm * 128 + wr * 64 + m * 16 + 4 * g;
#pragma unroll
        for (int n = 0; n < 4; n++) {
            const int col = bn * 128 + wc * 64 + n * 16 + c;
            const float bv = bias[col];
#pragma unroll
            for (int i = 0; i < 4; i++) {
                float v = acc[m][n][i] + bv;
                if constexpr (MODE == MODE_GELU) {
                    ((u16*)out0)[(size_t)(row + i) * N + col] = f2bf(fast_gelu(v));
                } else if constexpr (MODE == MODE_RESF32) {
                    const size_t idx = (size_t)(row + i) * N + col;
                    ((float*)out0)[idx] = v + res[idx];
                } else {
                    const int sect = (col >= 768) ? 1 : 0;
                    const int colm = col - sect * 768;
                    u16* dst = sect ? (u16*)out1 : (u16*)out0;
                    dst[(size_t)(row + i) * 768 + colm] = f2bf(v);
                }
            }
        }
    }
}

// ---------------------------------------------------------------------------
// Flash attention v4 (unchanged from round 9).
// ---------------------------------------------------------------------------
__global__ __launch_bounds__(256) void attn_kernel(
    const u16* __restrict__ Qg, const u16* __restrict__ Kg,
    const u16* __restrict__ Vt_g, u16* __restrict__ O)
{
    __shared__ u16 Kl[2][4096];
    __shared__ u16 Vl[2][4096];
    const int t = threadIdx.x, lane = t & 63, wave = t >> 6;
    const int g = lane >> 4, c = lane & 15;
    const int l = blockIdx.x;
    const int pos = l >> 3;
    const int b = l & 7, h = pos >> 4;
    const int qt = pos & 15;
    const int bh = b * 12 + h;
    const size_t rowb = (size_t)b * 1024;
    const int q0 = qt * 64 + wave * 16;

    bf16x8 qa[2];
    {
        const u16* qp = Qg + (rowb + q0 + c) * 768 + h * 64 + g * 8;
        u16x8 a0 = *(const u16x8*)qp;
        u16x8 a1 = *(const u16x8*)(qp + 32);
        bf16x8 va0, va1;
#pragma unroll
        for (int j = 0; j < 8; j++) {
            const float SC = 0.18033688011112042f;   // 0.125 * log2(e)
            va0[j] = (__bf16)(__uint_as_float(((u32)a0[j]) << 16) * SC);
            va1[j] = (__bf16)(__uint_as_float(((u32)a1[j]) << 16) * SC);
        }
        qa[0] = va0; qa[1] = va1;
    }

    int kro[4], kxo[4], vro[4];
#pragma unroll
    for (int n = 0; n < 4; n++) {
        const int pr = ((n >> 1) << 5) + ((c >> 2) << 3) + ((n & 1) << 2) + (c & 3);
        kro[n] = pr << 6;
        kxo[n] = (((pr >> 3) & 1) << 2) | (pr & 3);
        vro[n] = (n * 16 + c) << 6;
    }
    const int vxo = (((c >> 3) & 1) << 2) | (c & 3);

    const u16* ksrc = Kg + rowb * 768 + h * 64;
    const u16* vsrc = Vt_g + (size_t)bh * 65536;

    float m0 = -1e30f, l0 = 0.f;
    f32x4 oa[4] = {};
    const int srcb = (lane & 48) | ((lane >> 2) & 12);

    stage64(ksrc, 768, Kl[0], t);
    stage64(vsrc, 1024, Vl[0], t);
    __syncthreads();

    for (int kvt = 0; kvt < 16; ++kvt) {
        const u16* Kc = Kl[kvt & 1];
        const u16* Vc = Vl[kvt & 1];
        if (kvt < 15) {
            stage64(ksrc + (size_t)(kvt + 1) * 64 * 768, 768, Kl[(kvt + 1) & 1], t);
            stage64(vsrc + (kvt + 1) * 64, 1024, Vl[(kvt + 1) & 1], t);
        }

        f32x4 s0[4] = {};
        __builtin_amdgcn_s_setprio(1);
#pragma unroll
        for (int n = 0; n < 4; n++) {
#pragma unroll
            for (int kk = 0; kk < 2; kk++) {
                const bf16x8 kf = *(const bf16x8*)&Kc[kro[n] + ((((kk << 2) + g) ^ kxo[n]) << 3)];
                s0[n] = __builtin_amdgcn_mfma_f32_16x16x32_bf16(kf, qa[kk], s0[n], 0, 0, 0);
            }
        }
        __builtin_amdgcn_s_setprio(0);

        bf16x8 pa00, pa01;
        {
            float t0 = fmaxf(fmaxf(s0[0][0], s0[0][1]), fmaxf(s0[0][2], s0[0][3]));
            float t1 = fmaxf(fmaxf(s0[1][0], s0[1][1]), fmaxf(s0[1][2], s0[1][3]));
            float t2 = fmaxf(fmaxf(s0[2][0], s0[2][1]), fmaxf(s0[2][2], s0[2][3]));
            float t3 = fmaxf(fmaxf(s0[3][0], s0[3][1]), fmaxf(s0[3][2], s0[3][3]));
            float mx = fmaxf(fmaxf(t0, t1), fmaxf(t2, t3));
            mx = fmaxf(mx, __shfl_xor(mx, 16, 64));
            mx = fmaxf(mx, __shfl_xor(mx, 32, 64));
            if (!__all(mx <= m0 + 8.0f)) {
                const float mn = fmaxf(m0, mx);
                const float rsc = exp2f(m0 - mn);
                m0 = mn; l0 *= rsc;
                f32x4 rq;
#pragma unroll
                for (int i = 0; i < 4; i++) rq[i] = __shfl(rsc, srcb + i, 64);
#pragma unroll
                for (int n = 0; n < 4; n++) oa[n] *= rq;
            }
            float r = 0.f;
#pragma unroll
            for (int n = 0; n < 4; n++)
#pragma unroll
                for (int i = 0; i < 4; i++) {
                    s0[n][i] = exp2f(s0[n][i] - m0);
                    r += s0[n][i];
                }
            r += __shfl_xor(r, 16, 64);
            r += __shfl_xor(r, 32, 64);
            l0 += r;
#pragma unroll
            for (int i = 0; i < 4; i++) {
                pa00[i] = (__bf16)s0[0][i]; pa00[4 + i] = (__bf16)s0[1][i];
                pa01[i] = (__bf16)s0[2][i]; pa01[4 + i] = (__bf16)s0[3][i];
            }
        }

        __builtin_amdgcn_s_setprio(1);
#pragma unroll
        for (int n = 0; n < 4; n++) {
#pragma unroll
            for (int kk = 0; kk < 2; kk++) {
                const bf16x8 vf = *(const bf16x8*)&Vc[vro[n] + ((((kk << 2) + g) ^ vxo) << 3)];
                oa[n] = __builtin_amdgcn_mfma_f32_16x16x32_bf16(kk ? pa01 : pa00, vf, oa[n], 0, 0, 0);
            }
        }
        __builtin_amdgcn_s_setprio(0);
        __syncthreads();
    }

#pragma unroll
    for (int i = 0; i < 4; i++) {
        const float la = __shfl(l0, srcb + i, 64);
        const float ia_ = 1.0f / fmaxf(la, 1e-30f);
        const size_t ra_ = rowb + q0 + 4 * g + i;
#pragma unroll
        for (int n = 0; n < 4; n++)
            O[ra_ * 768 + h * 64 + n * 16 + c] = f2bf(oa[n][i] * ia_);
    }
}

// ---------------------------------------------------------------------------
// Launch
// ---------------------------------------------------------------------------
extern "C" void kernel_launch(void* const* d_in, const int* in_sizes, int n_in,
                              void* d_out, int out_size, void* d_ws, size_t ws_size,
                              hipStream_t stream)
{
    const float* x   = (const float*)d_in[0];
    const float* wq  = (const float*)d_in[1];
    const float* bq  = (const float*)d_in[2];
    const float* wk  = (const float*)d_in[3];
    const float* bk  = (const float*)d_in[4];
    const float* wv  = (const float*)d_in[5];
    const float* bv  = (const float*)d_in[6];
    const float* wo  = (const float*)d_in[7];
    const float* bo  = (const float*)d_in[8];
    const float* w1  = (const float*)d_in[9];
    const float* b1  = (const float*)d_in[10];
    const float* w2  = (const float*)d_in[11];
    const float* b2  = (const float*)d_in[12];
    const float* g1  = (const float*)d_in[13];
    const float* be1 = (const float*)d_in[14];
    const float* g2  = (const float*)d_in[15];
    const float* be2 = (const float*)d_in[16];

    char* ws = (char*)d_ws;
    constexpr size_t O_WQKV = 0;                       // [2304][768] bf16
    constexpr size_t O_WO   = 3538944;                 // [768][768]  bf16
    constexpr size_t O_W1   = 4718592;                 // [3072][768] bf16
    constexpr size_t O_W2   = 9437184;                 // [768][3072] bf16
    constexpr size_t O_BQKV = 14155776;                // [2304] f32
    constexpr size_t O_XLN  = 14168064;                // [8192][768] bf16
    constexpr size_t O_Q    = O_XLN + 12582912;
    constexpr size_t O_K    = O_Q + 12582912;
    constexpr size_t O_VT   = O_K + 12582912;          // [96][64][1024] bf16
    constexpr size_t O_ATTN = O_VT + 12582912;
    constexpr size_t O_H    = O_ATTN + 12582912;       // [8192][768] f32
    constexpr size_t O_F    = O_XLN;                   // overlays xln..VT
    constexpr size_t O_HLN  = O_ATTN;                  // overlays attnb

    u16* wqkvT = (u16*)(ws + O_WQKV);
    u16* woT   = (u16*)(ws + O_WO);
    u16* w1T   = (u16*)(ws + O_W1);
    u16* w2T   = (u16*)(ws + O_W2);
    float* bqkv = (float*)(ws + O_BQKV);
    u16* xln   = (u16*)(ws + O_XLN);
    u16* Qb    = (u16*)(ws + O_Q);
    u16* Kb    = (u16*)(ws + O_K);
    u16* VTg   = (u16*)(ws + O_VT);
    u16* attnb = (u16*)(ws + O_ATTN);
    float* h   = (float*)(ws + O_H);
    u16* fb    = (u16*)(ws + O_F);
    u16* hln   = (u16*)(ws + O_HLN);

    dim3 blk(256);
    prep_kernel<<<6921 + 8192, blk, 0, stream>>>(wq, wk, wv, wo, w1, w2, bq, bk, bv,
                                                 wqkvT, woT, w1T, w2T, bqkv,
                                                 x, xln, g1, be1);
    gemm_kernel<MODE_QKV><<<dim3(64, 18), blk, 0, stream>>>(
        xln, wqkvT, bqkv, nullptr, Qb, Kb, VTg, 8192, 2304, 768);
    attn_kernel<<<1536, blk, 0, stream>>>(Qb, Kb, VTg, attnb);
    gemm_kernel<MODE_RESF32><<<dim3(64, 6), blk, 0, stream>>>(
        attnb, woT, bo, x, h, nullptr, nullptr, 8192, 768, 768);
    ln_kernel<<<8192, blk, 0, stream>>>(h, hln, g2, be2);
    gemm_kernel<MODE_GELU><<<dim3(64, 24), blk, 0, stream>>>(
        hln, w1T, b1, nullptr, fb, nullptr, nullptr, 8192, 3072, 768);
    gemm_kernel<MODE_RESF32><<<dim3(64, 6), blk, 0, stream>>>(
        fb, w2T, b2, h, (float*)d_out, nullptr, nullptr, 8192, 768, 3072);
}

// Round 11
// 237.701 us; speedup vs baseline: 1.8377x; 1.0204x over previous
//
#include <hip/hip_runtime.h>
#include <hip/hip_bf16.h>
#include <math.h>

typedef unsigned short u16;
typedef unsigned int u32;
typedef u16 u16x8 __attribute__((ext_vector_type(8)));
typedef __bf16 bf16x8 __attribute__((ext_vector_type(8)));
typedef float f32x4 __attribute__((ext_vector_type(4)));

#define MODE_GELU 1
#define MODE_RESF32 2
#define MODE_QKV 3

template <typename T, typename F>
__device__ __forceinline__ T bitcast(F f) { return __builtin_bit_cast(T, f); }

__device__ __forceinline__ u16 f2bf(float f) {
    unsigned int u = __float_as_uint(f);
    u = (u + 0x7fffu + ((u >> 16) & 1u)) >> 16;
    return (u16)u;
}

__device__ __forceinline__ u32 packbf(float lo, float hi) {
    return (u32)f2bf(lo) | ((u32)f2bf(hi) << 16);
}

// branch-free GELU: x * sigmoid(1.5957691(x + 0.044715 x^3)); |err| vs exact
// erf-GELU ~3e-3 (<< 0.1256 threshold).
__device__ __forceinline__ float fast_gelu(float x) {
    const float arg = x * (2.30220775f + 0.10294329f * x * x);
    const float e = exp2f(arg);
    return x * (1.0f - __builtin_amdgcn_rcpf(e + 1.0f));
}

__device__ __forceinline__ void gl_lds16(const u16* g, u16* l) {
    __builtin_amdgcn_global_load_lds(
        (const __attribute__((address_space(1))) unsigned int*)(const void*)g,
        (__attribute__((address_space(3))) unsigned int*)(void*)l,
        16, 0, 0);
}

// Stage a 64-row x 64-col (u16) tile into LDS, XOR-swizzling the SOURCE so a
// later read of (row, slot^f(row)) returns logical (row, slot).
__device__ __forceinline__ void stage64(const u16* __restrict__ src, int stride,
                                        u16* __restrict__ lds, int t)
{
    const int wave = t >> 6, lane = t & 63;
#pragma unroll
    for (int i = 0; i < 2; i++) {
        const int row = i * 32 + wave * 8 + (lane >> 3);
        const int s = lane & 7;
        const int f = (((row >> 3) & 1) << 2) | (row & 3);
        gl_lds16(src + (size_t)row * stride + (size_t)((s ^ f) << 3),
                 lds + i * 2048 + wave * 512);
    }
}

// ---------------------------------------------------------------------------
// prep: 6 weight transposes + bias concat + LN1 (all pre-QKV work, one launch)
// ---------------------------------------------------------------------------
__global__ __launch_bounds__(256) void prep_kernel(
    const float* __restrict__ wq, const float* __restrict__ wk,
    const float* __restrict__ wv, const float* __restrict__ wo,
    const float* __restrict__ w1, const float* __restrict__ w2,
    const float* __restrict__ bq, const float* __restrict__ bk,
    const float* __restrict__ bv,
    u16* __restrict__ wqkvT, u16* __restrict__ woT,
    u16* __restrict__ w1T, u16* __restrict__ w2T, float* __restrict__ bqkv,
    const float* __restrict__ X, u16* __restrict__ Y,
    const float* __restrict__ gp, const float* __restrict__ bp)
{
    const int blk = blockIdx.x;
    if (blk >= 6921) {
        // ---- LN1 row ----
        __shared__ float sbuf[8];
        const int row = blk - 6921, t = threadIdx.x;
        const float* xr = X + (size_t)row * 768;
        float v0 = xr[t], v1 = xr[t + 256], v2 = xr[t + 512];
        float s = v0 + v1 + v2;
        float q = v0 * v0 + v1 * v1 + v2 * v2;
#pragma unroll
        for (int m = 1; m < 64; m <<= 1) {
            s += __shfl_xor(s, m, 64);
            q += __shfl_xor(q, m, 64);
        }
        const int wave = t >> 6, lane = t & 63;
        if (lane == 0) { sbuf[wave] = s; sbuf[4 + wave] = q; }
        __syncthreads();
        s = sbuf[0] + sbuf[1] + sbuf[2] + sbuf[3];
        q = sbuf[4] + sbuf[5] + sbuf[6] + sbuf[7];
        const float mean = s * (1.0f / 768.0f);
        float ssd = fmaxf(q - 768.0f * mean * mean, 0.0f);
        const float stdv = sqrtf(ssd * (1.0f / 767.0f));
        const float scale = gp[0] / (stdv + 1e-5f);
        const float beta = bp[0];
        u16* yr = Y + (size_t)row * 768;
        yr[t]       = f2bf((v0 - mean) * scale + beta);
        yr[t + 256] = f2bf((v1 - mean) * scale + beta);
        yr[t + 512] = f2bf((v2 - mean) * scale + beta);
        return;
    }
    if (blk >= 6912) {
        const int t = (blk - 6912) * 256 + threadIdx.x;
        if (t < 2304)
            bqkv[t] = t < 768 ? bq[t] : (t < 1536 ? bk[t - 768] : bv[t - 1536]);
        return;
    }
    const float* W; u16* WT; int Krows, Ncols, lt;
    if (blk < 576)       { W = wq; WT = wqkvT;                       Krows = 768;  Ncols = 768;  lt = blk; }
    else if (blk < 1152) { W = wk; WT = wqkvT + (size_t)768 * 768;   Krows = 768;  Ncols = 768;  lt = blk - 576; }
    else if (blk < 1728) { W = wv; WT = wqkvT + (size_t)1536 * 768;  Krows = 768;  Ncols = 768;  lt = blk - 1152; }
    else if (blk < 2304) { W = wo; WT = woT;                         Krows = 768;  Ncols = 768;  lt = blk - 1728; }
    else if (blk < 4608) { W = w1; WT = w1T;                         Krows = 768;  Ncols = 3072; lt = blk - 2304; }
    else                 { W = w2; WT = w2T;                         Krows = 3072; Ncols = 768;  lt = blk - 4608; }
    const int ktiles = Krows >> 5;
    const int k0 = (lt % ktiles) * 32, n0 = (lt / ktiles) * 32;

    __shared__ float tile[32][33];
    const int tx = threadIdx.x & 31, ty = threadIdx.x >> 5;
#pragma unroll
    for (int j = 0; j < 32; j += 8)
        tile[ty + j][tx] = W[(size_t)(k0 + ty + j) * Ncols + n0 + tx];
    __syncthreads();
#pragma unroll
    for (int j = 0; j < 32; j += 8)
        WT[(size_t)(n0 + ty + j) * Krows + k0 + tx] = f2bf(tile[tx][ty + j]);
}

// ---------------------------------------------------------------------------
// LayerNorm (standalone, for LN2)
// ---------------------------------------------------------------------------
__global__ __launch_bounds__(256) void ln_kernel(
    const float* __restrict__ X, u16* __restrict__ Y,
    const float* __restrict__ gp, const float* __restrict__ bp)
{
    __shared__ float sbuf[8];
    const int row = blockIdx.x, t = threadIdx.x;
    const float* xr = X + (size_t)row * 768;
    float v0 = xr[t], v1 = xr[t + 256], v2 = xr[t + 512];
    float s = v0 + v1 + v2;
    float q = v0 * v0 + v1 * v1 + v2 * v2;
#pragma unroll
    for (int m = 1; m < 64; m <<= 1) {
        s += __shfl_xor(s, m, 64);
        q += __shfl_xor(q, m, 64);
    }
    const int wave = t >> 6, lane = t & 63;
    if (lane == 0) { sbuf[wave] = s; sbuf[4 + wave] = q; }
    __syncthreads();
    s = sbuf[0] + sbuf[1] + sbuf[2] + sbuf[3];
    q = sbuf[4] + sbuf[5] + sbuf[6] + sbuf[7];
    const float mean = s * (1.0f / 768.0f);
    float ssd = fmaxf(q - 768.0f * mean * mean, 0.0f);
    const float stdv = sqrtf(ssd * (1.0f / 767.0f));
    const float scale = gp[0] / (stdv + 1e-5f);
    const float beta = bp[0];
    u16* yr = Y + (size_t)row * 768;
    yr[t]       = f2bf((v0 - mean) * scale + beta);
    yr[t + 256] = f2bf((v1 - mean) * scale + beta);
    yr[t + 512] = f2bf((v2 - mean) * scale + beta);
}

// ---------------------------------------------------------------------------
// GEMM v4: 2-phase dbuf + both-sides LDS swizzle + XCD bm-chunk swizzle.
// XCD k owns bm in [8k, 8k+8): its A-panel (<=1.6MB @K=768) stays L2-resident.
// Bijective: all grids are 64 x Y with 64*Y % 8 == 0.
// ---------------------------------------------------------------------------
template <int MODE>
__global__ __launch_bounds__(256) void gemm_kernel(
    const u16* __restrict__ A, const u16* __restrict__ BT,
    const float* __restrict__ bias, const float* __restrict__ res,
    void* __restrict__ out0, void* __restrict__ out1, void* __restrict__ out2,
    int M, int N, int K)
{
    __shared__ u16 sh[2][2][128 * 64];
    u16* shp = &sh[0][0][0];
    const int t = threadIdx.x;
    const int lane = t & 63, wave = t >> 6;
    const int wr = wave >> 1, wc = wave & 1;
    const int g = lane >> 4, c = lane & 15;

    // XCD-aware block remap (lin%8 = XCD round-robin slot)
    const int lin = blockIdx.x + blockIdx.y * gridDim.x;
    const int xcd = lin & 7, idx = lin >> 3;
    const int bm = xcd * 8 + (idx & 7);
    const int bn = idx >> 3;

    const int srow = wave * 32 + (lane >> 3);   // + it*8 at use
    const u16* Ag = A + (size_t)(bm * 128 + srow) * K;
    const u16* Bg = BT + (size_t)(bn * 128 + srow) * K;

    // read-side swizzle constant: f(row)=((c>>3)<<2)|(c&3) since row%16==c
    const int fc = (((c >> 3) & 1) << 2) | (c & 3);
    const int xs0 = (g ^ fc) << 3;              // slot kk=0
    const int xs1 = ((4 + g) ^ fc) << 3;        // slot kk=1

    f32x4 acc[4][4] = {};
    const int nk = K >> 6;

    // stage-side: it-th issue covers rows wave*32+it*8+(lane>>3)
    const int sl = lane & 7;
    int sco[4];
#pragma unroll
    for (int it = 0; it < 4; it++)
        sco[it] = ((sl ^ (((it & 1) << 2) | ((lane >> 3) & 3))) << 3);

#define STAGE_AB(buf, k0)                                                     \
    {                                                                         \
        _Pragma("unroll")                                                     \
        for (int it = 0; it < 4; it++) {                                      \
            gl_lds16(Ag + (size_t)(it * 8) * K + (k0) + sco[it], &sh[buf][0][wave * 2048 + it * 512]); \
            gl_lds16(Bg + (size_t)(it * 8) * K + (k0) + sco[it], &sh[buf][1][wave * 2048 + it * 512]); \
        }                                                                     \
    }

    STAGE_AB(0, 0);
    __syncthreads();

    for (int ks = 0; ks < nk; ks++) {
        const int cur = ks & 1;
        if (ks + 1 < nk) STAGE_AB(cur ^ 1, (ks + 1) << 6);
        const u16* Asb = sh[cur][0];
        const u16* Bsb = sh[cur][1];
        __builtin_amdgcn_s_setprio(1);
#pragma unroll
        for (int kk = 0; kk < 2; kk++) {
            const int xo = kk ? xs1 : xs0;
            bf16x8 af[4], bfr[4];
#pragma unroll
            for (int m = 0; m < 4; m++)
                af[m] = *(const bf16x8*)&Asb[(wr * 64 + m * 16 + c) * 64 + xo];
#pragma unroll
            for (int n = 0; n < 4; n++)
                bfr[n] = *(const bf16x8*)&Bsb[(wc * 64 + n * 16 + c) * 64 + xo];
#pragma unroll
            for (int m = 0; m < 4; m++)
#pragma unroll
                for (int n = 0; n < 4; n++)
                    acc[m][n] = __builtin_amdgcn_mfma_f32_16x16x32_bf16(
                        af[m], bfr[n], acc[m][n], 0, 0, 0);
        }
        __builtin_amdgcn_s_setprio(0);
        __syncthreads();
    }
#undef STAGE_AB

    if constexpr (MODE == MODE_QKV) {
        if (bn >= 12) {
            // ---- V section: LDS tile transpose, coalesced V^T stores ----
#pragma unroll
            for (int m = 0; m < 4; m++) {
#pragma unroll
                for (int n = 0; n < 4; n++) {
                    const int colL = wc * 64 + n * 16 + c;
                    const int rowLb = wr * 64 + m * 16 + 4 * g;
                    const float bv = bias[bn * 128 + colL];
                    const u32 x0 = packbf(acc[m][n][0] + bv, acc[m][n][1] + bv);
                    const u32 x1 = packbf(acc[m][n][2] + bv, acc[m][n][3] + bv);
                    const int elem = colL * 128 + (rowLb ^ ((colL & 15) << 3));
                    ((u32*)shp)[elem >> 1] = x0;
                    ((u32*)shp)[(elem >> 1) + 1] = x1;
                }
            }
            __syncthreads();
            const int bn_off = bn - 12;
            const int bb = bm >> 3, kvb = (bm & 7) * 128;
            const int j8 = (t & 7) * 8;
#pragma unroll
            for (int it = 0; it < 4; it++) {
                const int colL2 = it * 32 + (t >> 3);
                const int gcol = bn_off * 128 + colL2;
                const int hh = gcol >> 6, d = gcol & 63;
                const size_t obase = ((size_t)(bb * 12 + hh) << 16) + ((size_t)d << 10) + kvb;
                const int X = (colL2 & 15) << 3;
#pragma unroll
                for (int half = 0; half < 2; half++) {
                    const int rowL2 = half * 64 + j8;
                    const int elem = colL2 * 128 + (rowL2 ^ X);
                    *(u16x8*)((u16*)out2 + obase + rowL2) = *(const u16x8*)&shp[elem];
                }
            }
            return;
        }
    }

#pragma unroll
    for (int m = 0; m < 4; m++) {
        const int row = bm * 128 + wr * 64 + m * 16 + 4 * g;
#pragma unroll
        for (int n = 0; n < 4; n++) {
            const int col = bn * 128 + wc * 64 + n * 16 + c;
            const float bv = bias[col];
#pragma unroll
            for (int i = 0; i < 4; i++) {
                float v = acc[m][n][i] + bv;
                if constexpr (MODE == MODE_GELU) {
                    ((u16*)out0)[(size_t)(row + i) * N + col] = f2bf(fast_gelu(v));
                } else if constexpr (MODE == MODE_RESF32) {
                    const size_t idx = (size_t)(row + i) * N + col;
                    ((float*)out0)[idx] = v + res[idx];
                } else {
                    const int sect = (col >= 768) ? 1 : 0;
                    const int colm = col - sect * 768;
                    u16* dst = sect ? (u16*)out1 : (u16*)out0;
                    dst[(size_t)(row + i) * 768 + colm] = f2bf(v);
                }
            }
        }
    }
}

// ---------------------------------------------------------------------------
// Flash attention v5: row-sums via ones-MFMA (l in the C-layout, no shuffles),
// max3-chain reduce, defer-max, dbuf swizzled staging, XCD head mapping.
// ---------------------------------------------------------------------------
__global__ __launch_bounds__(256) void attn_kernel(
    const u16* __restrict__ Qg, const u16* __restrict__ Kg,
    const u16* __restrict__ Vt_g, u16* __restrict__ O)
{
    __shared__ u16 Kl[2][4096];
    __shared__ u16 Vl[2][4096];
    const int t = threadIdx.x, lane = t & 63, wave = t >> 6;
    const int g = lane >> 4, c = lane & 15;
    const int l = blockIdx.x;
    const int pos = l >> 3;
    const int b = l & 7, h = pos >> 4;
    const int qt = pos & 15;
    const int bh = b * 12 + h;
    const size_t rowb = (size_t)b * 1024;
    const int q0 = qt * 64 + wave * 16;

    bf16x8 qa[2];
    {
        const u16* qp = Qg + (rowb + q0 + c) * 768 + h * 64 + g * 8;
        u16x8 a0 = *(const u16x8*)qp;
        u16x8 a1 = *(const u16x8*)(qp + 32);
        bf16x8 va0, va1;
#pragma unroll
        for (int j = 0; j < 8; j++) {
            const float SC = 0.18033688011112042f;   // 0.125 * log2(e)
            va0[j] = (__bf16)(__uint_as_float(((u32)a0[j]) << 16) * SC);
            va1[j] = (__bf16)(__uint_as_float(((u32)a1[j]) << 16) * SC);
        }
        qa[0] = va0; qa[1] = va1;
    }

    bf16x8 vone;
#pragma unroll
    for (int j = 0; j < 8; j++) vone[j] = (__bf16)1.0f;

    int kro[4], kxo[4], vro[4];
#pragma unroll
    for (int n = 0; n < 4; n++) {
        const int pr = ((n >> 1) << 5) + ((c >> 2) << 3) + ((n & 1) << 2) + (c & 3);
        kro[n] = pr << 6;
        kxo[n] = (((pr >> 3) & 1) << 2) | (pr & 3);
        vro[n] = (n * 16 + c) << 6;
    }
    const int vxo = (((c >> 3) & 1) << 2) | (c & 3);

    const u16* ksrc = Kg + rowb * 768 + h * 64;
    const u16* vsrc = Vt_g + (size_t)bh * 65536;

    float m0 = -1e30f;
    f32x4 oa[4] = {};
    f32x4 lsum = {};
    const int srcb = (lane & 48) | ((lane >> 2) & 12);

    stage64(ksrc, 768, Kl[0], t);
    stage64(vsrc, 1024, Vl[0], t);
    __syncthreads();

    for (int kvt = 0; kvt < 16; ++kvt) {
        const u16* Kc = Kl[kvt & 1];
        const u16* Vc = Vl[kvt & 1];
        if (kvt < 15) {
            stage64(ksrc + (size_t)(kvt + 1) * 64 * 768, 768, Kl[(kvt + 1) & 1], t);
            stage64(vsrc + (kvt + 1) * 64, 1024, Vl[(kvt + 1) & 1], t);
        }

        f32x4 s0[4] = {};
        __builtin_amdgcn_s_setprio(1);
#pragma unroll
        for (int n = 0; n < 4; n++) {
#pragma unroll
            for (int kk = 0; kk < 2; kk++) {
                const bf16x8 kf = *(const bf16x8*)&Kc[kro[n] + ((((kk << 2) + g) ^ kxo[n]) << 3)];
                s0[n] = __builtin_amdgcn_mfma_f32_16x16x32_bf16(kf, qa[kk], s0[n], 0, 0, 0);
            }
        }
        __builtin_amdgcn_s_setprio(0);

        bf16x8 pa00, pa01;
        {
            // max3-fusable chain reduce over the 16 lane-local scores
            float mx = fmaxf(fmaxf(s0[0][0], s0[0][1]), s0[0][2]);
            mx = fmaxf(fmaxf(mx, s0[0][3]), s0[1][0]);
            mx = fmaxf(fmaxf(mx, s0[1][1]), s0[1][2]);
            mx = fmaxf(fmaxf(mx, s0[1][3]), s0[2][0]);
            mx = fmaxf(fmaxf(mx, s0[2][1]), s0[2][2]);
            mx = fmaxf(fmaxf(mx, s0[2][3]), s0[3][0]);
            mx = fmaxf(fmaxf(mx, s0[3][1]), s0[3][2]);
            mx = fmaxf(mx, s0[3][3]);
            mx = fmaxf(mx, __shfl_xor(mx, 16, 64));
            mx = fmaxf(mx, __shfl_xor(mx, 32, 64));
            if (!__all(mx <= m0 + 8.0f)) {
                const float mn = fmaxf(m0, mx);
                const float rsc = exp2f(m0 - mn);
                m0 = mn;
                f32x4 rq;
#pragma unroll
                for (int i = 0; i < 4; i++) rq[i] = __shfl(rsc, srcb + i, 64);
#pragma unroll
                for (int n = 0; n < 4; n++) oa[n] *= rq;
                lsum *= rq;
            }
#pragma unroll
            for (int n = 0; n < 4; n++)
#pragma unroll
                for (int i = 0; i < 4; i++)
                    s0[n][i] = exp2f(s0[n][i] - m0);
#pragma unroll
            for (int i = 0; i < 4; i++) {
                pa00[i] = (__bf16)s0[0][i]; pa00[4 + i] = (__bf16)s0[1][i];
                pa01[i] = (__bf16)s0[2][i]; pa01[4 + i] = (__bf16)s0[3][i];
            }
        }

        __builtin_amdgcn_s_setprio(1);
        // row-sums ride the MFMA pipe (lsum[i] matches oa[n][i]'s q-row)
        lsum = __builtin_amdgcn_mfma_f32_16x16x32_bf16(pa00, vone, lsum, 0, 0, 0);
        lsum = __builtin_amdgcn_mfma_f32_16x16x32_bf16(pa01, vone, lsum, 0, 0, 0);
#pragma unroll
        for (int n = 0; n < 4; n++) {
#pragma unroll
            for (int kk = 0; kk < 2; kk++) {
                const bf16x8 vf = *(const bf16x8*)&Vc[vro[n] + ((((kk << 2) + g) ^ vxo) << 3)];
                oa[n] = __builtin_amdgcn_mfma_f32_16x16x32_bf16(kk ? pa01 : pa00, vf, oa[n], 0, 0, 0);
            }
        }
        __builtin_amdgcn_s_setprio(0);
        __syncthreads();
    }

#pragma unroll
    for (int i = 0; i < 4; i++) {
        const float ia_ = 1.0f / fmaxf(lsum[i], 1e-30f);
        const size_t ra_ = rowb + q0 + 4 * g + i;
#pragma unroll
        for (int n = 0; n < 4; n++)
            O[ra_ * 768 + h * 64 + n * 16 + c] = f2bf(oa[n][i] * ia_);
    }
}

// ---------------------------------------------------------------------------
// Launch
// ---------------------------------------------------------------------------
extern "C" void kernel_launch(void* const* d_in, const int* in_sizes, int n_in,
                              void* d_out, int out_size, void* d_ws, size_t ws_size,
                              hipStream_t stream)
{
    const float* x   = (const float*)d_in[0];
    const float* wq  = (const float*)d_in[1];
    const float* bq  = (const float*)d_in[2];
    const float* wk  = (const float*)d_in[3];
    const float* bk  = (const float*)d_in[4];
    const float* wv  = (const float*)d_in[5];
    const float* bv  = (const float*)d_in[6];
    const float* wo  = (const float*)d_in[7];
    const float* bo  = (const float*)d_in[8];
    const float* w1  = (const float*)d_in[9];
    const float* b1  = (const float*)d_in[10];
    const float* w2  = (const float*)d_in[11];
    const float* b2  = (const float*)d_in[12];
    const float* g1  = (const float*)d_in[13];
    const float* be1 = (const float*)d_in[14];
    const float* g2  = (const float*)d_in[15];
    const float* be2 = (const float*)d_in[16];

    char* ws = (char*)d_ws;
    constexpr size_t O_WQKV = 0;                       // [2304][768] bf16
    constexpr size_t O_WO   = 3538944;                 // [768][768]  bf16
    constexpr size_t O_W1   = 4718592;                 // [3072][768] bf16
    constexpr size_t O_W2   = 9437184;                 // [768][3072] bf16
    constexpr size_t O_BQKV = 14155776;                // [2304] f32
    constexpr size_t O_XLN  = 14168064;                // [8192][768] bf16
    constexpr size_t O_Q    = O_XLN + 12582912;
    constexpr size_t O_K    = O_Q + 12582912;
    constexpr size_t O_VT   = O_K + 12582912;          // [96][64][1024] bf16
    constexpr size_t O_ATTN = O_VT + 12582912;
    constexpr size_t O_H    = O_ATTN + 12582912;       // [8192][768] f32
    constexpr size_t O_F    = O_XLN;                   // overlays xln..VT
    constexpr size_t O_HLN  = O_ATTN;                  // overlays attnb

    u16* wqkvT = (u16*)(ws + O_WQKV);
    u16* woT   = (u16*)(ws + O_WO);
    u16* w1T   = (u16*)(ws + O_W1);
    u16* w2T   = (u16*)(ws + O_W2);
    float* bqkv = (float*)(ws + O_BQKV);
    u16* xln   = (u16*)(ws + O_XLN);
    u16* Qb    = (u16*)(ws + O_Q);
    u16* Kb    = (u16*)(ws + O_K);
    u16* VTg   = (u16*)(ws + O_VT);
    u16* attnb = (u16*)(ws + O_ATTN);
    float* h   = (float*)(ws + O_H);
    u16* fb    = (u16*)(ws + O_F);
    u16* hln   = (u16*)(ws + O_HLN);

    dim3 blk(256);
    prep_kernel<<<6921 + 8192, blk, 0, stream>>>(wq, wk, wv, wo, w1, w2, bq, bk, bv,
                                                 wqkvT, woT, w1T, w2T, bqkv,
                                                 x, xln, g1, be1);
    gemm_kernel<MODE_QKV><<<dim3(64, 18), blk, 0, stream>>>(
        xln, wqkvT, bqkv, nullptr, Qb, Kb, VTg, 8192, 2304, 768);
    attn_kernel<<<1536, blk, 0, stream>>>(Qb, Kb, VTg, attnb);
    gemm_kernel<MODE_RESF32><<<dim3(64, 6), blk, 0, stream>>>(
        attnb, woT, bo, x, h, nullptr, nullptr, 8192, 768, 768);
    ln_kernel<<<8192, blk, 0, stream>>>(h, hln, g2, be2);
    gemm_kernel<MODE_GELU><<<dim3(64, 24), blk, 0, stream>>>(
        hln, w1T, b1, nullptr, fb, nullptr, nullptr, 8192, 3072, 768);
    gemm_kernel<MODE_RESF32><<<dim3(64, 6), blk, 0, stream>>>(
        fb, w2T, b2, h, (float*)d_out, nullptr, nullptr, 8192, 768, 3072);
}